// Round 2
// baseline (2338.567 us; speedup 1.0000x reference)
//
#include <hip/hip_runtime.h>
#include <cstddef>
#include <cstdint>

#define B_ 64
#define N_ 128
#define FIN_ 768
#define NFEAT_ 1024
#define NHID_ 512
#define NHEADS_ 8
#define NCLASS_ 512
#define NEG_E_ (-9.0e15f)
#define NEG_S_ (-9.0e10f)

// ---------------------------------------------------------------------------
// Stage 1: group pooling. grid (C, 6), block 128 (one f-chunk of 128 per blockIdx.y)
// Pointers are pre-offset to the chunk's first batch.
// ---------------------------------------------------------------------------
__global__ __launch_bounds__(128) void group_pool_kernel(
    const float* __restrict__ x, const int* __restrict__ offs,
    float* __restrict__ x_off, int* __restrict__ ig)
{
  const int b = blockIdx.x;
  const int fc = blockIdx.y;
  const int tid = threadIdx.x;
  __shared__ int o0[N_], o1[N_];
  __shared__ int endk[N_ + 2];
  __shared__ int Gs;
  o0[tid] = offs[(b * N_ + tid) * 2 + 0];
  o1[tid] = offs[(b * N_ + tid) * 2 + 1];
  __syncthreads();
  if (tid == 0) {
    int fz = N_;
    for (int k = 0; k < N_; ++k) { if (o0[k] == 0 && o1[k] == 0) { fz = k; break; } }
    int g = 0;
    endk[0] = 0;
    for (int k = 0; k < fz; ++k) {
      int nxt = (k + 1 < N_) ? o0[k + 1] : 0;
      if (o1[k] == nxt - 1 && g < N_) { endk[g + 1] = k + 1; ++g; }  // word boundary
    }
    Gs = g;
  }
  __syncthreads();
  const int G = Gs;
  const int f = fc * 128 + tid;
  for (int g = 0; g < N_; ++g) {
    float v = 0.0f;
    if (g < G) {
      int s = endk[g], e = endk[g + 1];
      float acc = 0.0f;
      for (int k = s; k < e; ++k) acc += x[((size_t)b * N_ + k) * FIN_ + f];
      v = acc / (float)(e - s);
    }
    x_off[((size_t)b * N_ + g) * FIN_ + f] = v;
  }
  if (fc == 0) {
    int g = tid;
    int s = (g < G) ? endk[g] : 0;
    int e = (g < G) ? endk[g + 1] : 0;
    ig[(b * N_ + g) * 2 + 0] = s;
    ig[(b * N_ + g) * 2 + 1] = e;
  }
}

// ---------------------------------------------------------------------------
// fp32 GEMM, 128x128 tile, BK=16, 256 threads, 8x8 per thread. C = A*B + bias.
// M,N multiples of 128; K multiple of 16.
// B element (k, n) is at Bm[(n/hw)*hs + (n%hw) + k*ldb] — hw/hs express the
// head-blocked hW_w (8,1024,512) layout without a transpose pass; standard
// GEMMs pass ldb=N, hw=N, hs=0.
// ---------------------------------------------------------------------------
__global__ __launch_bounds__(256) void gemm_bias_f32(
    const float* __restrict__ A, const float* __restrict__ Bm,
    const float* __restrict__ bias, float* __restrict__ C,
    int M, int N, int K, int ldb, int hw, long long hs)
{
  __shared__ float As[16][128];  // As[k][m]
  __shared__ float Bs[16][128];  // Bs[k][n]
  const int tid = threadIdx.x;
  const int bm = blockIdx.y * 128;
  const int bn = blockIdx.x * 128;
  const int ty = tid >> 4, tx = tid & 15;
  const int ar = tid >> 2, ac = (tid & 3) * 4;
  const int br = tid >> 5, bc = (tid & 31) * 4;
  const float* Ap0 = A + (size_t)(bm + ar) * K + ac;
  const float* Ap1 = A + (size_t)(bm + ar + 64) * K + ac;
  const float* Bbase = Bm + (size_t)(bn / hw) * hs + (bn % hw);
  const float* Bp0 = Bbase + (size_t)br * ldb + bc;
  const float* Bp1 = Bbase + (size_t)(br + 8) * ldb + bc;
  float acc[8][8];
#pragma unroll
  for (int i = 0; i < 8; ++i)
#pragma unroll
    for (int j = 0; j < 8; ++j) acc[i][j] = 0.0f;

  for (int k0 = 0; k0 < K; k0 += 16) {
    float4 a0 = *(const float4*)(Ap0 + k0);
    float4 a1 = *(const float4*)(Ap1 + k0);
    float4 b0 = *(const float4*)(Bp0 + (size_t)k0 * ldb);
    float4 b1 = *(const float4*)(Bp1 + (size_t)k0 * ldb);
    __syncthreads();
    As[ac + 0][ar] = a0.x; As[ac + 1][ar] = a0.y; As[ac + 2][ar] = a0.z; As[ac + 3][ar] = a0.w;
    As[ac + 0][ar + 64] = a1.x; As[ac + 1][ar + 64] = a1.y; As[ac + 2][ar + 64] = a1.z; As[ac + 3][ar + 64] = a1.w;
    *(float4*)&Bs[br][bc] = b0;
    *(float4*)&Bs[br + 8][bc] = b1;
    __syncthreads();
#pragma unroll
    for (int kk = 0; kk < 16; ++kk) {
      float a[8], bb[8];
      *(float4*)(a)      = *(const float4*)&As[kk][ty * 8];
      *(float4*)(a + 4)  = *(const float4*)&As[kk][ty * 8 + 4];
      *(float4*)(bb)     = *(const float4*)&Bs[kk][tx * 8];
      *(float4*)(bb + 4) = *(const float4*)&Bs[kk][tx * 8 + 4];
#pragma unroll
      for (int i = 0; i < 8; ++i)
#pragma unroll
        for (int j = 0; j < 8; ++j)
          acc[i][j] = fmaf(a[i], bb[j], acc[i][j]);
    }
  }
  float bv[8];
#pragma unroll
  for (int j = 0; j < 8; ++j) bv[j] = bias[bn + tx * 8 + j];
#pragma unroll
  for (int i = 0; i < 8; ++i) {
    int row = bm + ty * 8 + i;
    float4 v0, v1;
    v0.x = acc[i][0] + bv[0]; v0.y = acc[i][1] + bv[1];
    v0.z = acc[i][2] + bv[2]; v0.w = acc[i][3] + bv[3];
    v1.x = acc[i][4] + bv[4]; v1.y = acc[i][5] + bv[5];
    v1.z = acc[i][6] + bv[6]; v1.w = acc[i][7] + bv[7];
    float* Cr = C + (size_t)row * N + bn + tx * 8;
    *(float4*)(Cr) = v0;
    *(float4*)(Cr + 4) = v1;
  }
}

// ---------------------------------------------------------------------------
// Per-row attention src/dst dots: one wave per row of X (R x 512).
// W has H rows of 1024 (src half | dst half).  Output layout [b][h][n]
// (b chunk-local).
// ---------------------------------------------------------------------------
__global__ __launch_bounds__(256) void dot_pairs_kernel(
    const float* __restrict__ X, const float* __restrict__ W,
    float* __restrict__ esrc, float* __restrict__ edst, int H, int R)
{
  int wave = (blockIdx.x * 256 + threadIdx.x) >> 6;
  int lane = threadIdx.x & 63;
  if (wave >= R) return;
  const float* xr = X + (size_t)wave * 512;
  const float* wr = W + (size_t)(wave % H) * 1024;
  float s1 = 0.0f, s2 = 0.0f;
#pragma unroll
  for (int i = 0; i < 8; ++i) {
    int o = lane + i * 64;
    float xv = xr[o];
    s1 = fmaf(xv, wr[o], s1);
    s2 = fmaf(xv, wr[512 + o], s2);
  }
  for (int off = 32; off; off >>= 1) {
    s1 += __shfl_down(s1, off);
    s2 += __shfl_down(s2, off);
  }
  if (lane == 0) {
    int hd = wave % H, bn = wave / H;
    int bb = bn >> 7, n = bn & 127;
    int oi = (bb * H + hd) * 128 + n;
    esrc[oi] = s1;
    edst[oi] = s2;
  }
}

// ---------------------------------------------------------------------------
// Edge softmax: one wave per (b,h,i) row; j in [0,128). adj pre-offset to chunk.
// ---------------------------------------------------------------------------
__global__ __launch_bounds__(64) void edge_softmax_kernel(
    const float* __restrict__ esrc, const float* __restrict__ edst,
    const float* __restrict__ bias, const float* __restrict__ adj,
    float* __restrict__ att, int H)
{
  int row = blockIdx.x;            // (b*H + hd)*128 + i  (b chunk-local)
  int lane = threadIdx.x;
  int i = row & 127;
  int bh = row >> 7;
  int hd = bh % H;
  int b = bh / H;
  float es = esrc[row] + bias[hd];
  const float* adjr = adj + ((size_t)b * N_ + i) * N_;
  const float* edr = edst + (size_t)bh * N_;
  float v[2];
#pragma unroll
  for (int t = 0; t < 2; ++t) {
    int j = lane + t * 64;
    float e = es + edr[j];
    e = (e >= 0.0f) ? e : 0.2f * e;        // leaky_relu, alpha=0.2
    v[t] = (adjr[j] > 0.0f) ? e : NEG_E_;
  }
  float mx = fmaxf(v[0], v[1]);
  for (int off = 32; off; off >>= 1) mx = fmaxf(mx, __shfl_xor(mx, off));
  float e0 = expf(v[0] - mx), e1 = expf(v[1] - mx);
  float sm = e0 + e1;
  for (int off = 32; off; off >>= 1) sm += __shfl_xor(sm, off);
  float inv = 1.0f / sm;
  float* ar = att + (size_t)row * N_;
  ar[lane] = e0 * inv;
  ar[lane + 64] = e1 * inv;
}

// ---------------------------------------------------------------------------
// Batched GEMM + ELU: C = elu(A(128x128) * B(128xNcols)). 64x64 tiles, BK=16.
// grid.x = 2*(Ncols/64) tiles, grid.y = z (chunkBatches*heads).
// ---------------------------------------------------------------------------
__global__ __launch_bounds__(256) void bgemm_elu_f32(
    const float* __restrict__ Abase, const float* __restrict__ Bbase,
    float* __restrict__ Cbase, int H,
    long long sBb, long long sBh, int ldb,
    long long sCb, long long sCh, int ldc, int Ncols)
{
  __shared__ float As[16][64];
  __shared__ float Bs[16][64];
  const int tid = threadIdx.x;
  const int ntn = Ncols >> 6;
  const int tm = blockIdx.x / ntn, tn = blockIdx.x % ntn;
  const int bm = tm * 64, bn = tn * 64;
  const int z = blockIdx.y;
  const int b = z / H, hd = z % H;
  const float* A = Abase + (size_t)z * (N_ * N_);
  const float* Bb = Bbase + (size_t)b * sBb + (size_t)hd * sBh;
  float* C = Cbase + (size_t)b * sCb + (size_t)hd * sCh;
  const int ty = tid >> 4, tx = tid & 15;
  const int ar = tid >> 2, ac = (tid & 3) * 4;
  const int br = tid >> 4, bc = (tid & 15) * 4;
  const float* Ap = A + (size_t)(bm + ar) * N_ + ac;
  const float* Bp = Bb + (size_t)br * ldb + bn + bc;
  float acc[4][4];
#pragma unroll
  for (int i = 0; i < 4; ++i)
#pragma unroll
    for (int j = 0; j < 4; ++j) acc[i][j] = 0.0f;

  for (int k0 = 0; k0 < N_; k0 += 16) {
    float4 av = *(const float4*)(Ap + k0);
    float4 bvv = *(const float4*)(Bp + (size_t)k0 * ldb);
    __syncthreads();
    As[ac + 0][ar] = av.x; As[ac + 1][ar] = av.y; As[ac + 2][ar] = av.z; As[ac + 3][ar] = av.w;
    *(float4*)&Bs[br][bc] = bvv;
    __syncthreads();
#pragma unroll
    for (int kk = 0; kk < 16; ++kk) {
      float a[4], bb[4];
      *(float4*)a  = *(const float4*)&As[kk][ty * 4];
      *(float4*)bb = *(const float4*)&Bs[kk][tx * 4];
#pragma unroll
      for (int i = 0; i < 4; ++i)
#pragma unroll
        for (int j = 0; j < 4; ++j)
          acc[i][j] = fmaf(a[i], bb[j], acc[i][j]);
    }
  }
#pragma unroll
  for (int i = 0; i < 4; ++i) {
    int row = bm + ty * 4 + i;
    float t0 = acc[i][0], t1 = acc[i][1], t2 = acc[i][2], t3 = acc[i][3];
    float4 v;
    v.x = t0 > 0.0f ? t0 : expm1f(t0);     // elu (alpha=1)
    v.y = t1 > 0.0f ? t1 : expm1f(t1);
    v.z = t2 > 0.0f ? t2 : expm1f(t2);
    v.w = t3 > 0.0f ? t3 : expm1f(t3);
    *(float4*)(C + (size_t)row * ldc + bn + tx * 4) = v;
  }
}

// ---------------------------------------------------------------------------
// logits = x2 @ fin_w + fin_b  (one wave per row)
// ---------------------------------------------------------------------------
__global__ __launch_bounds__(256) void logits_kernel(
    const float* __restrict__ X, const float* __restrict__ w,
    const float* __restrict__ bptr, float* __restrict__ out, int R)
{
  int wave = (blockIdx.x * 256 + threadIdx.x) >> 6;
  int lane = threadIdx.x & 63;
  if (wave >= R) return;
  const float* xr = X + (size_t)wave * 512;
  float s = 0.0f;
#pragma unroll
  for (int i = 0; i < 8; ++i) {
    int c = lane + i * 64;
    s = fmaf(xr[c], w[c], s);
  }
  for (int off = 32; off; off >>= 1) s += __shfl_down(s, off);
  if (lane == 0) out[wave] = s + bptr[0];
}

// ---------------------------------------------------------------------------
// Final stage: scores (two softmaxes) -> stable rank -> gather fix -> expand.
// One block of 128 threads per batch.
// ---------------------------------------------------------------------------
__global__ __launch_bounds__(128) void finalize_kernel(
    const float* __restrict__ logits, const float* __restrict__ tag,
    const float* __restrict__ amask, const int* __restrict__ ig,
    int* __restrict__ out)
{
  const int b = blockIdx.x, tid = threadIdx.x;
  __shared__ float red[N_];
  __shared__ float scs[N_];
  __shared__ int fs[N_], fe[N_], lens[N_], csum[N_];
  __shared__ int redi[N_];

  float lg = logits[b * N_ + tid];
  float tg = tag[b * N_ + tid];
  float am = amask[b * N_ + tid];
  float m = (tg > 0.0f) ? am : 0.0f;

  // sc = softmax(where(m>0, logits*m, NEG_S))
  float in1 = (m > 0.0f) ? lg * m : NEG_S_;
  red[tid] = in1; __syncthreads();
  for (int s = 64; s > 0; s >>= 1) { if (tid < s) red[tid] = fmaxf(red[tid], red[tid + s]); __syncthreads(); }
  float M1 = red[0]; __syncthreads();
  float e1 = expf(in1 - M1);
  red[tid] = e1; __syncthreads();
  for (int s = 64; s > 0; s >>= 1) { if (tid < s) red[tid] += red[tid + s]; __syncthreads(); }
  float S1 = red[0]; __syncthreads();
  float sc = e1 / S1;

  // summary = sum(m)
  red[tid] = m; __syncthreads();
  for (int s = 64; s > 0; s >>= 1) { if (tid < s) red[tid] += red[tid + s]; __syncthreads(); }
  float SM = red[0]; __syncthreads();

  // ii = softmax(where(m>0, (N-l)/summary*m, NEG_S))
  float in2 = (m > 0.0f) ? ((float)(N_ - tid) / SM) * m : NEG_S_;
  red[tid] = in2; __syncthreads();
  for (int s = 64; s > 0; s >>= 1) { if (tid < s) red[tid] = fmaxf(red[tid], red[tid + s]); __syncthreads(); }
  float M2 = red[0]; __syncthreads();
  float e2 = expf(in2 - M2);
  red[tid] = e2; __syncthreads();
  for (int s = 64; s > 0; s >>= 1) { if (tid < s) red[tid] += red[tid + s]; __syncthreads(); }
  float S2 = red[0]; __syncthreads();
  float ii = e2 / S2;

  scs[tid] = sc + ii;
  __syncthreads();

  // stable descending rank (matches stable jnp.argsort(-sc))
  float si = scs[tid];
  int rank = 0;
  for (int j = 0; j < N_; ++j) {
    float sj = scs[j];
    rank += (sj > si) || (sj == si && j < tid);
  }
  // fix[b, j] = index_group[b, rank[j]]
  fs[tid] = ig[(b * N_ + rank) * 2 + 0];
  fe[tid] = ig[(b * N_ + rank) * 2 + 1];
  __syncthreads();

  // expand
  redi[tid] = (fs[tid] == 0 && fe[tid] == 0) ? tid : N_;
  __syncthreads();
  for (int s = 64; s > 0; s >>= 1) { if (tid < s) redi[tid] = min(redi[tid], redi[tid + s]); __syncthreads(); }
  int fz = redi[0]; __syncthreads();
  lens[tid] = (tid < fz) ? (fe[tid] - fs[tid]) : 0;
  __syncthreads();
  if (tid == 0) {
    int r = 0;
    for (int k = 0; k < N_; ++k) { r += lens[k]; csum[k] = r; }
  }
  __syncthreads();
  int total = csum[N_ - 1];
  int l = tid;
  int k = 0;
  while (k < N_ && csum[k] <= l) ++k;
  if (k > N_ - 1) k = N_ - 1;
  int val = fs[k] + (l - (csum[k] - lens[k]));
  out[b * N_ + l] = (l < total) ? val : l;
}

// ---------------------------------------------------------------------------
extern "C" void kernel_launch(void* const* d_in, const int* in_sizes, int n_in,
                              void* d_out, int out_size, void* d_ws, size_t ws_size,
                              hipStream_t stream)
{
  const float* x     = (const float*)d_in[0];
  const float* tag   = (const float*)d_in[1];
  const int*   offs  = (const int*)  d_in[2];
  const float* amask = (const float*)d_in[3];
  const float* adj   = (const float*)d_in[4];
  const float* Wg_w  = (const float*)d_in[5];
  const float* Wg_b  = (const float*)d_in[6];
  const float* hW_w  = (const float*)d_in[7];
  const float* hW_b  = (const float*)d_in[8];
  const float* ha_w  = (const float*)d_in[9];
  const float* ha_b  = (const float*)d_in[10];
  const float* oW_w  = (const float*)d_in[11];
  const float* oW_b  = (const float*)d_in[12];
  const float* oa_w  = (const float*)d_in[13];
  const float* oa_b  = (const float*)d_in[14];
  const float* fin_w = (const float*)d_in[15];
  const float* fin_b = (const float*)d_in[16];
  int* out = (int*)d_out;

  // ---- ws_size-adaptive batch chunking ----
  // Persistent: ig (128 KB) + h2 (16 MB). Per-chunk pool for C batches:
  //   x_off_c  C*393216 B
  //   xw_c     C*524288 B
  //   h_c      C*2097152 B
  //   att_c    C*524288 B
  //   x1_c     C*2097152 B
  //   esrc/edst C*4096 B each
  // Stage 2 reuses the pool: att2 (4 MB) + x2 (16 MB) + e2s/e2d/lgts (96 KB).
  const size_t PER_CHUNK = 5644288;        // bytes per batch in the pool
  const size_t STAGE2    = 4194304 + 16777216 + 3 * 32768;
  const size_t FIXED     = 131072 + 16777216 + 4096;  // ig + h2 + slack
  int C = 4;
  for (int cand = 64; cand >= 4; cand >>= 1) {
    size_t pool = (size_t)cand * PER_CHUNK;
    if (pool < STAGE2) pool = STAGE2;
    if (FIXED + pool <= ws_size) { C = cand; break; }
  }

  char* ws = (char*)d_ws;
  size_t o = 0;
  int*   ig = (int*)(ws + o);   o += 131072;
  float* h2 = (float*)(ws + o); o += 16777216;
  char*  pool = ws + o;

  // chunk-pool carve
  size_t po = 0;
  float* x_off_c = (float*)(pool + po); po += (size_t)C * 393216;
  float* xw_c    = (float*)(pool + po); po += (size_t)C * 524288;
  float* h_c     = (float*)(pool + po); po += (size_t)C * 2097152;
  float* att_c   = (float*)(pool + po); po += (size_t)C * 524288;
  float* x1_c    = (float*)(pool + po); po += (size_t)C * 2097152;
  float* esrc_c  = (float*)(pool + po); po += (size_t)C * 4096;
  float* edst_c  = (float*)(pool + po); po += (size_t)C * 4096;

  // stage-2 carve (pool reused after chunk loop)
  float* att2 = (float*)(pool + 0);
  float* x2   = (float*)(pool + 4194304);
  float* e2s  = (float*)(pool + 4194304 + 16777216);
  float* e2d  = e2s + 8192;
  float* lgts = e2d + 8192;

  const int R = C * 128;  // rows per chunk

  for (int b0 = 0; b0 < B_; b0 += C) {
    const float* x_ch    = x    + (size_t)b0 * N_ * FIN_;
    const int*   offs_ch = offs + (size_t)b0 * N_ * 2;
    const float* adj_ch  = adj  + (size_t)b0 * N_ * N_;
    int*         ig_ch   = ig   + (size_t)b0 * N_ * 2;
    float*       h2_ch   = h2   + (size_t)b0 * N_ * 512;

    // 1. group pool -> x_off_c, ig
    group_pool_kernel<<<dim3(C, 6), 128, 0, stream>>>(x_ch, offs_ch, x_off_c, ig_ch);
    // 2. xw = x_off @ Wg_w + Wg_b            (R x 1024, K=768)
    gemm_bias_f32<<<dim3(8, C), 256, 0, stream>>>(
        x_off_c, Wg_w, Wg_b, xw_c, R, 1024, 768, 1024, 1024, 0);
    // 3. h = xw @ hW_w(head-blocked) + hW_b  (R x 4096, K=1024), layout (b,n,head,o)
    gemm_bias_f32<<<dim3(32, C), 256, 0, stream>>>(
        xw_c, hW_w, hW_b, h_c, R, 4096, 1024, 512, 512, (long long)1024 * 512);
    // 4. esrc/edst per (b,n,head)
    dot_pairs_kernel<<<C * 256, 256, 0, stream>>>(h_c, ha_w, esrc_c, edst_c, NHEADS_, R * NHEADS_);
    // 5. att = softmax(mask(leaky_relu(esrc_i + edst_j + ha_b)))
    edge_softmax_kernel<<<C * NHEADS_ * N_, 64, 0, stream>>>(esrc_c, edst_c, ha_b, adj_ch, att_c, NHEADS_);
    // 6. x1 = elu(att @ h)   batched over (b,head), stored (b,n,head,o)
    bgemm_elu_f32<<<dim3(16, C * NHEADS_), 256, 0, stream>>>(att_c, h_c, x1_c, NHEADS_,
        (long long)128 * 4096, 512, 4096, (long long)128 * 4096, 512, 4096, 512);
    // 7. h2 rows = x1 @ oW_w + oW_b          (R x 512, K=4096)
    gemm_bias_f32<<<dim3(4, C), 256, 0, stream>>>(
        x1_c, oW_w, oW_b, h2_ch, R, 512, 4096, 512, 512, 0);
  }

  // 8. e2src/e2dst per (b,n)
  dot_pairs_kernel<<<2048, 256, 0, stream>>>(h2, oa_w, e2s, e2d, 1, 8192);
  // 9. att2
  edge_softmax_kernel<<<8192, 64, 0, stream>>>(e2s, e2d, oa_b, adj, att2, 1);
  // 10. x2 = elu(att2 @ h2)   batched over b
  bgemm_elu_f32<<<dim3(16, 64), 256, 0, stream>>>(att2, h2, x2, 1,
      (long long)128 * 512, 0, 512, (long long)128 * 512, 0, 512, 512);
  // 11. logits = x2 @ fin_w + fin_b
  logits_kernel<<<2048, 256, 0, stream>>>(x2, fin_w, fin_b, lgts, 8192);
  // 12. scores -> rank -> fix -> expand -> out (int32)
  finalize_kernel<<<B_, 128, 0, stream>>>(lgts, tag, amask, ig, out);
}

// Round 5
// 1828.355 us; speedup vs baseline: 1.2791x; 1.2791x over previous
//
#include <hip/hip_runtime.h>
#include <cstddef>
#include <cstdint>

#define B_ 64
#define N_ 128
#define FIN_ 768
#define NEG_E_ (-9.0e15f)
#define NEG_S_ (-9.0e10f)
#define CHUNK_ 16

typedef unsigned short u16;
typedef unsigned int u32;
typedef float f32x4 __attribute__((ext_vector_type(4)));
typedef short s16x8 __attribute__((ext_vector_type(8)));   // 8 bf16 (guide-verified frag type)
typedef u16 u16x4 __attribute__((ext_vector_type(4)));

__device__ __forceinline__ u16 f2bf(float x) {
  u32 u = __float_as_uint(x);
  return (u16)((u + 0x7fffu + ((u >> 16) & 1u)) >> 16);
}
__device__ __forceinline__ float b2f(u16 h) {
  return __uint_as_float(((u32)h) << 16);
}

// ---------------------------------------------------------------------------
// Group pooling -> x_off split bf16 (hi/lo) + index_group. Chunk-local b.
// ---------------------------------------------------------------------------
__global__ __launch_bounds__(128) void group_pool_kernel(
    const float* __restrict__ x, const int* __restrict__ offs,
    u16* __restrict__ xoh, u16* __restrict__ xol, int* __restrict__ ig)
{
  const int b = blockIdx.x;
  const int fc = blockIdx.y;
  const int tid = threadIdx.x;
  __shared__ int o0[N_], o1[N_];
  __shared__ int endk[N_ + 2];
  __shared__ int Gs;
  o0[tid] = offs[(b * N_ + tid) * 2 + 0];
  o1[tid] = offs[(b * N_ + tid) * 2 + 1];
  __syncthreads();
  if (tid == 0) {
    int fz = N_;
    for (int k = 0; k < N_; ++k) { if (o0[k] == 0 && o1[k] == 0) { fz = k; break; } }
    int g = 0;
    endk[0] = 0;
    for (int k = 0; k < fz; ++k) {
      int nxt = (k + 1 < N_) ? o0[k + 1] : 0;
      if (o1[k] == nxt - 1 && g < N_) { endk[g + 1] = k + 1; ++g; }
    }
    Gs = g;
  }
  __syncthreads();
  const int G = Gs;
  const int f = fc * 128 + tid;
  for (int g = 0; g < N_; ++g) {
    float v = 0.0f;
    if (g < G) {
      int s = endk[g], e = endk[g + 1];
      float acc = 0.0f;
      for (int k = s; k < e; ++k) acc += x[((size_t)b * N_ + k) * FIN_ + f];
      v = acc / (float)(e - s);
    }
    u16 hh = f2bf(v);
    size_t oo = ((size_t)b * N_ + g) * FIN_ + f;
    xoh[oo] = hh;
    xol[oo] = f2bf(v - b2f(hh));
  }
  if (fc == 0) {
    int g = tid;
    int s = (g < G) ? endk[g] : 0;
    int e = (g < G) ? endk[g + 1] : 0;
    ig[(b * N_ + g) * 2 + 0] = s;
    ig[(b * N_ + g) * 2 + 1] = e;
  }
}

// ---------------------------------------------------------------------------
// Weight pack/transpose/split kernels
// ---------------------------------------------------------------------------
__global__ __launch_bounds__(256) void pack_wgT(  // Wg_w[768][1024] -> WgT[1024][768]
    const float* __restrict__ w, u16* __restrict__ th, u16* __restrict__ tl)
{
  int idx = blockIdx.x * 256 + threadIdx.x;
  float v = w[idx];
  int k = idx >> 10, n = idx & 1023;
  u16 h = f2bf(v);
  th[n * 768 + k] = h;
  tl[n * 768 + k] = f2bf(v - b2f(h));
}
__global__ __launch_bounds__(256) void pack_hwT(  // hW_w[8][1024][512] -> hWT[4096][1024]
    const float* __restrict__ w, u16* __restrict__ th, u16* __restrict__ tl)
{
  int idx = blockIdx.x * 256 + threadIdx.x;
  float v = w[idx];
  int hd = idx >> 19, f = (idx >> 9) & 1023, o = idx & 511;
  int dst = (hd * 512 + o) * 1024 + f;
  u16 h = f2bf(v);
  th[dst] = h;
  tl[dst] = f2bf(v - b2f(h));
}
__global__ __launch_bounds__(256) void pack_owT(  // oW_w[4096][512] -> oWT[512][4096]
    const float* __restrict__ w, u16* __restrict__ th, u16* __restrict__ tl)
{
  int idx = blockIdx.x * 256 + threadIdx.x;
  float v = w[idx];
  int k = idx >> 9, o = idx & 511;
  int dst = o * 4096 + k;
  u16 h = f2bf(v);
  th[dst] = h;
  tl[dst] = f2bf(v - b2f(h));
}

// ---------------------------------------------------------------------------
// Split-bf16 MFMA GEMM. C[m][n] = sum_k (Ah+Al)[m][k]*(Bh+Bl)[k][n] (3-term).
// A: row-major M x K (hi/lo).  B: BT layout, row-major N x K (hi/lo).
// Output: off = (m>>msh)*s_mb + (m&mmask) + (n>>nsh)*s_nb + (n&nmask)*s_n
//   + (z/zH)*zb_s + (z%zH)*zh_s.   128x128 tile, 4 waves (2x2 of 64x64),
// per-wave 4x4 frags of 16x16x32.  Staging: register round-trip; LDS rows
// padded to 40 u16 (80 B, 16B-aligned, bank starts (8r)%32... <=2-way free).
// ---------------------------------------------------------------------------
__global__ __launch_bounds__(256) void mfma_split_gemm(
    const u16* __restrict__ Ah, const u16* __restrict__ Al,
    const u16* __restrict__ Bh, const u16* __restrict__ Bl,
    const float* __restrict__ bias, int bias_mode,   // 0 none, 1 per-n, 2 per-m
    u16* __restrict__ Oh, u16* __restrict__ Ol, float* __restrict__ Of,
    int out_f32, int do_elu,
    int K,
    long long Az, long long Bz,
    int msh, long long s_mb, int nsh, long long s_nb, long long s_n,
    long long zb_s, long long zh_s, int zH)
{
  __shared__ u16 As_h[128][40];
  __shared__ u16 As_l[128][40];
  __shared__ u16 Bs_h[128][40];
  __shared__ u16 Bs_l[128][40];
  const int tid = threadIdx.x;
  const int wave = tid >> 6, lane = tid & 63;
  const int wm = (wave >> 1) * 64, wn = (wave & 1) * 64;
  const int bn = blockIdx.x * 128, bm = blockIdx.y * 128;
  const int z = blockIdx.z;
  const u16* Ahb = Ah + (long long)z * Az;
  const u16* Alb = Al + (long long)z * Az;
  const u16* Bhb = Bh + (long long)z * Bz;
  const u16* Blb = Bl + (long long)z * Bz;
  const int lm = lane & 15, lq = lane >> 4;

  // staging coords: thread covers row sr, u16 cols [sc, sc+16)
  const int sr = tid >> 1;
  const int sc = (tid & 1) * 16;
  const size_t ga = (size_t)(bm + sr) * K + sc;
  const size_t gb = (size_t)(bn + sr) * K + sc;

  f32x4 acc[4][4];
#pragma unroll
  for (int i = 0; i < 4; ++i)
#pragma unroll
    for (int j = 0; j < 4; ++j) acc[i][j] = (f32x4){0.0f, 0.0f, 0.0f, 0.0f};

  for (int k0 = 0; k0 < K; k0 += 32) {
    uint4 vah0 = *(const uint4*)(Ahb + ga + k0);
    uint4 vah1 = *(const uint4*)(Ahb + ga + k0 + 8);
    uint4 val0 = *(const uint4*)(Alb + ga + k0);
    uint4 val1 = *(const uint4*)(Alb + ga + k0 + 8);
    uint4 vbh0 = *(const uint4*)(Bhb + gb + k0);
    uint4 vbh1 = *(const uint4*)(Bhb + gb + k0 + 8);
    uint4 vbl0 = *(const uint4*)(Blb + gb + k0);
    uint4 vbl1 = *(const uint4*)(Blb + gb + k0 + 8);
    __syncthreads();
    *(uint4*)&As_h[sr][sc] = vah0;
    *(uint4*)&As_h[sr][sc + 8] = vah1;
    *(uint4*)&As_l[sr][sc] = val0;
    *(uint4*)&As_l[sr][sc + 8] = val1;
    *(uint4*)&Bs_h[sr][sc] = vbh0;
    *(uint4*)&Bs_h[sr][sc + 8] = vbh1;
    *(uint4*)&Bs_l[sr][sc] = vbl0;
    *(uint4*)&Bs_l[sr][sc + 8] = vbl1;
    __syncthreads();
    s16x8 fa_h[4], fa_l[4], fb_h[4], fb_l[4];
#pragma unroll
    for (int t = 0; t < 4; ++t) {
      fa_h[t] = *(const s16x8*)&As_h[wm + t * 16 + lm][lq * 8];
      fa_l[t] = *(const s16x8*)&As_l[wm + t * 16 + lm][lq * 8];
      fb_h[t] = *(const s16x8*)&Bs_h[wn + t * 16 + lm][lq * 8];
      fb_l[t] = *(const s16x8*)&Bs_l[wn + t * 16 + lm][lq * 8];
    }
#pragma unroll
    for (int i = 0; i < 4; ++i)
#pragma unroll
      for (int j = 0; j < 4; ++j) {
        acc[i][j] = __builtin_amdgcn_mfma_f32_16x16x32_bf16(fa_h[i], fb_h[j], acc[i][j], 0, 0, 0);
        acc[i][j] = __builtin_amdgcn_mfma_f32_16x16x32_bf16(fa_h[i], fb_l[j], acc[i][j], 0, 0, 0);
        acc[i][j] = __builtin_amdgcn_mfma_f32_16x16x32_bf16(fa_l[i], fb_h[j], acc[i][j], 0, 0, 0);
      }
  }

  // epilogue: C row m = quad*4+reg (4 consecutive), col n = lane&15
  const long long zoff = (long long)(z / zH) * zb_s + (long long)(z % zH) * zh_s;
  const int mmask = (1 << msh) - 1;
  const int nmask = (1 << nsh) - 1;
#pragma unroll
  for (int i = 0; i < 4; ++i) {
    int mb = bm + wm + i * 16 + lq * 4;
#pragma unroll
    for (int j = 0; j < 4; ++j) {
      int n = bn + wn + j * 16 + lm;
      f32x4 v = acc[i][j];
      if (bias_mode == 1) {
        v += bias[n];
      } else if (bias_mode == 2) {
        f32x4 b4 = *(const f32x4*)&bias[mb];
        v += b4;
      }
      if (do_elu) {
        v.x = v.x > 0.0f ? v.x : expm1f(v.x);
        v.y = v.y > 0.0f ? v.y : expm1f(v.y);
        v.z = v.z > 0.0f ? v.z : expm1f(v.z);
        v.w = v.w > 0.0f ? v.w : expm1f(v.w);
      }
      long long off = (long long)(mb >> msh) * s_mb + (long long)(mb & mmask)
                    + (long long)(n >> nsh) * s_nb + (long long)(n & nmask) * s_n + zoff;
      if (out_f32) {
        *(f32x4*)(Of + off) = v;
      } else {
        u16 h0 = f2bf(v.x), h1 = f2bf(v.y), h2 = f2bf(v.z), h3 = f2bf(v.w);
        u16x4 hv = {h0, h1, h2, h3};
        u16x4 lv = {f2bf(v.x - b2f(h0)), f2bf(v.y - b2f(h1)),
                    f2bf(v.z - b2f(h2)), f2bf(v.w - b2f(h3))};
        *(u16x4*)(Oh + off) = hv;
        *(u16x4*)(Ol + off) = lv;
      }
    }
  }
}

// ---------------------------------------------------------------------------
// esrc/edst from hT (split bf16): one block per chunk-local (bc,head).
// ---------------------------------------------------------------------------
__global__ __launch_bounds__(128) void dot_pairs_hT(
    const u16* __restrict__ hTh, const u16* __restrict__ hTl,
    const float* __restrict__ W,   // ha_w [8][1024]
    float* __restrict__ esrc, float* __restrict__ edst)
{
  int bh = blockIdx.x;
  int head = bh & 7;
  int i = threadIdx.x;
  const u16* ph = hTh + (size_t)bh * 65536;
  const u16* pl = hTl + (size_t)bh * 65536;
  const float* w1 = W + head * 1024;
  float s1 = 0.0f, s2 = 0.0f;
  for (int o = 0; o < 512; ++o) {
    float hv = b2f(ph[o * 128 + i]) + b2f(pl[o * 128 + i]);
    s1 = fmaf(hv, w1[o], s1);
    s2 = fmaf(hv, w1[512 + o], s2);
  }
  esrc[bh * 128 + i] = s1;
  edst[bh * 128 + i] = s2;
}

// e2 dots from h2T (fp32): one block per b (global).
__global__ __launch_bounds__(128) void dot_pairs_h2T(
    const float* __restrict__ h2T, const float* __restrict__ oa,
    float* __restrict__ e2s, float* __restrict__ e2d)
{
  int b = blockIdx.x;
  int i = threadIdx.x;
  float s1 = 0.0f, s2 = 0.0f;
  for (int o = 0; o < 512; ++o) {
    float hv = h2T[(size_t)o * 8192 + b * 128 + i];
    s1 = fmaf(hv, oa[o], s1);
    s2 = fmaf(hv, oa[512 + o], s2);
  }
  e2s[b * 128 + i] = s1;
  e2d[b * 128 + i] = s2;
}

// ---------------------------------------------------------------------------
// Edge softmax; split=1 -> bf16 hi/lo output, else fp32.  adj pre-offset.
// ---------------------------------------------------------------------------
__global__ __launch_bounds__(64) void edge_softmax_kernel(
    const float* __restrict__ esrc, const float* __restrict__ edst,
    const float* __restrict__ bias, const float* __restrict__ adj,
    float* __restrict__ attf, u16* __restrict__ atth, u16* __restrict__ attl,
    int H, int split)
{
  int row = blockIdx.x;            // (b*H + hd)*128 + i  (b chunk-local)
  int lane = threadIdx.x;
  int i = row & 127;
  int bh = row >> 7;
  int hd = bh % H;
  int b = bh / H;
  float es = esrc[row] + bias[hd];
  const float* adjr = adj + ((size_t)b * N_ + i) * N_;
  const float* edr = edst + (size_t)bh * N_;
  float v[2];
#pragma unroll
  for (int t = 0; t < 2; ++t) {
    int j = lane + t * 64;
    float e = es + edr[j];
    e = (e >= 0.0f) ? e : 0.2f * e;
    v[t] = (adjr[j] > 0.0f) ? e : NEG_E_;
  }
  float mx = fmaxf(v[0], v[1]);
  for (int off = 32; off; off >>= 1) mx = fmaxf(mx, __shfl_xor(mx, off));
  float e0 = expf(v[0] - mx), e1 = expf(v[1] - mx);
  float sm = e0 + e1;
  for (int off = 32; off; off >>= 1) sm += __shfl_xor(sm, off);
  float inv = 1.0f / sm;
  float p0 = e0 * inv, p1 = e1 * inv;
  size_t base = (size_t)row * N_;
  if (split) {
    u16 h0 = f2bf(p0), h1 = f2bf(p1);
    atth[base + lane] = h0;
    attl[base + lane] = f2bf(p0 - b2f(h0));
    atth[base + lane + 64] = h1;
    attl[base + lane + 64] = f2bf(p1 - b2f(h1));
  } else {
    attf[base + lane] = p0;
    attf[base + lane + 64] = p1;
  }
}

// ---------------------------------------------------------------------------
// Stage-2 fp32 batched GEMM + ELU, B from transposed layout (h2T[512][8192]).
// x2[b,i,o] = elu(sum_j att2[b,i,j] * h2T[o][b*128+j]).  64x64 tiles, BK=16.
// ---------------------------------------------------------------------------
__global__ __launch_bounds__(256) void bgemm_elu_bt_f32(
    const float* __restrict__ A, const float* __restrict__ BT,
    float* __restrict__ C)
{
  __shared__ float As[16][64];
  __shared__ float Bs[16][68];
  const int tid = threadIdx.x;
  const int tm = blockIdx.x >> 3, tn = blockIdx.x & 7;
  const int bm = tm * 64, bn = tn * 64;
  const int b = blockIdx.y;
  const float* Ab = A + (size_t)b * 16384;
  const float* BTb = BT + (size_t)b * 128;
  const int ty = tid >> 4, tx = tid & 15;
  const int ar = tid >> 2, ac = (tid & 3) * 4;
  float acc[4][4];
#pragma unroll
  for (int i = 0; i < 4; ++i)
#pragma unroll
    for (int j = 0; j < 4; ++j) acc[i][j] = 0.0f;

  for (int k0 = 0; k0 < 128; k0 += 16) {
    float4 av = *(const float4*)(Ab + (size_t)(bm + ar) * 128 + k0 + ac);
    float4 bv = *(const float4*)(BTb + (size_t)(bn + ar) * 8192 + k0 + ac);
    __syncthreads();
    As[ac + 0][ar] = av.x; As[ac + 1][ar] = av.y; As[ac + 2][ar] = av.z; As[ac + 3][ar] = av.w;
    Bs[ac + 0][ar] = bv.x; Bs[ac + 1][ar] = bv.y; Bs[ac + 2][ar] = bv.z; Bs[ac + 3][ar] = bv.w;
    __syncthreads();
#pragma unroll
    for (int kk = 0; kk < 16; ++kk) {
      float a[4], bb[4];
      *(float4*)a  = *(const float4*)&As[kk][ty * 4];
      *(float4*)bb = *(const float4*)&Bs[kk][tx * 4];
#pragma unroll
      for (int i = 0; i < 4; ++i)
#pragma unroll
        for (int j = 0; j < 4; ++j)
          acc[i][j] = fmaf(a[i], bb[j], acc[i][j]);
    }
  }
#pragma unroll
  for (int i = 0; i < 4; ++i) {
    int row = b * 128 + bm + ty * 4 + i;
    float4 v;
    v.x = acc[i][0] > 0.0f ? acc[i][0] : expm1f(acc[i][0]);
    v.y = acc[i][1] > 0.0f ? acc[i][1] : expm1f(acc[i][1]);
    v.z = acc[i][2] > 0.0f ? acc[i][2] : expm1f(acc[i][2]);
    v.w = acc[i][3] > 0.0f ? acc[i][3] : expm1f(acc[i][3]);
    *(float4*)(C + (size_t)row * 512 + bn + tx * 4) = v;
  }
}

// ---------------------------------------------------------------------------
// logits = x2 @ fin_w + fin_b  (one wave per row)
// ---------------------------------------------------------------------------
__global__ __launch_bounds__(256) void logits_kernel(
    const float* __restrict__ X, const float* __restrict__ w,
    const float* __restrict__ bptr, float* __restrict__ out, int R)
{
  int wv = (blockIdx.x * 256 + threadIdx.x) >> 6;
  int lane = threadIdx.x & 63;
  if (wv >= R) return;
  const float* xr = X + (size_t)wv * 512;
  float s = 0.0f;
#pragma unroll
  for (int i = 0; i < 8; ++i) {
    int c = lane + i * 64;
    s = fmaf(xr[c], w[c], s);
  }
  for (int off = 32; off; off >>= 1) s += __shfl_down(s, off);
  if (lane == 0) out[wv] = s + bptr[0];
}

// ---------------------------------------------------------------------------
// Final: scores -> stable rank -> gather fix -> expand.
// ---------------------------------------------------------------------------
__global__ __launch_bounds__(128) void finalize_kernel(
    const float* __restrict__ logits, const float* __restrict__ tag,
    const float* __restrict__ amask, const int* __restrict__ ig,
    int* __restrict__ out)
{
  const int b = blockIdx.x, tid = threadIdx.x;
  __shared__ float red[N_];
  __shared__ float scs[N_];
  __shared__ int fs[N_], fe[N_], lens[N_], csum[N_];
  __shared__ int redi[N_];

  float lg = logits[b * N_ + tid];
  float tg = tag[b * N_ + tid];
  float am = amask[b * N_ + tid];
  float m = (tg > 0.0f) ? am : 0.0f;

  float in1 = (m > 0.0f) ? lg * m : NEG_S_;
  red[tid] = in1; __syncthreads();
  for (int s = 64; s > 0; s >>= 1) { if (tid < s) red[tid] = fmaxf(red[tid], red[tid + s]); __syncthreads(); }
  float M1 = red[0]; __syncthreads();
  float e1 = expf(in1 - M1);
  red[tid] = e1; __syncthreads();
  for (int s = 64; s > 0; s >>= 1) { if (tid < s) red[tid] += red[tid + s]; __syncthreads(); }
  float S1 = red[0]; __syncthreads();
  float sc = e1 / S1;

  red[tid] = m; __syncthreads();
  for (int s = 64; s > 0; s >>= 1) { if (tid < s) red[tid] += red[tid + s]; __syncthreads(); }
  float SM = red[0]; __syncthreads();

  float in2 = (m > 0.0f) ? ((float)(N_ - tid) / SM) * m : NEG_S_;
  red[tid] = in2; __syncthreads();
  for (int s = 64; s > 0; s >>= 1) { if (tid < s) red[tid] = fmaxf(red[tid], red[tid + s]); __syncthreads(); }
  float M2 = red[0]; __syncthreads();
  float e2 = expf(in2 - M2);
  red[tid] = e2; __syncthreads();
  for (int s = 64; s > 0; s >>= 1) { if (tid < s) red[tid] += red[tid + s]; __syncthreads(); }
  float S2 = red[0]; __syncthreads();
  float ii = e2 / S2;

  scs[tid] = sc + ii;
  __syncthreads();

  float si = scs[tid];
  int rank = 0;
  for (int j = 0; j < N_; ++j) {
    float sj = scs[j];
    rank += (sj > si) || (sj == si && j < tid);
  }
  fs[tid] = ig[(b * N_ + rank) * 2 + 0];
  fe[tid] = ig[(b * N_ + rank) * 2 + 1];
  __syncthreads();

  redi[tid] = (fs[tid] == 0 && fe[tid] == 0) ? tid : N_;
  __syncthreads();
  for (int s = 64; s > 0; s >>= 1) { if (tid < s) redi[tid] = min(redi[tid], redi[tid + s]); __syncthreads(); }
  int fz = redi[0]; __syncthreads();
  lens[tid] = (tid < fz) ? (fe[tid] - fs[tid]) : 0;
  __syncthreads();
  if (tid == 0) {
    int r = 0;
    for (int k = 0; k < N_; ++k) { r += lens[k]; csum[k] = r; }
  }
  __syncthreads();
  int total = csum[N_ - 1];
  int l = tid;
  int k = 0;
  while (k < N_ && csum[k] <= l) ++k;
  if (k > N_ - 1) k = N_ - 1;
  int val = fs[k] + (l - (csum[k] - lens[k]));
  out[b * N_ + l] = (l < total) ? val : l;
}

// ---------------------------------------------------------------------------
extern "C" void kernel_launch(void* const* d_in, const int* in_sizes, int n_in,
                              void* d_out, int out_size, void* d_ws, size_t ws_size,
                              hipStream_t stream)
{
  const float* x     = (const float*)d_in[0];
  const float* tag   = (const float*)d_in[1];
  const int*   offs  = (const int*)  d_in[2];
  const float* amask = (const float*)d_in[3];
  const float* adj   = (const float*)d_in[4];
  const float* Wg_w  = (const float*)d_in[5];
  const float* Wg_b  = (const float*)d_in[6];
  const float* hW_w  = (const float*)d_in[7];
  const float* hW_b  = (const float*)d_in[8];
  const float* ha_w  = (const float*)d_in[9];
  const float* ha_b  = (const float*)d_in[10];
  const float* oW_w  = (const float*)d_in[11];
  const float* oW_b  = (const float*)d_in[12];
  const float* oa_w  = (const float*)d_in[13];
  const float* oa_b  = (const float*)d_in[14];
  const float* fin_w = (const float*)d_in[15];
  const float* fin_b = (const float*)d_in[16];
  int* out = (int*)d_out;

  // ---- workspace: 121.3 MB total.  R1..R4 evidence: ws_size >= 197.5 MB
  // (R2 ran at C=32) and < 328 MB (R1/R3/R4 aborts = overflow). ----
  char* ws = (char*)d_ws;
  size_t o = 0;
  int* ig     = (int*)(ws + o);  o += 131072;
  u16* WgT_h  = (u16*)(ws + o);  o += 1572864;
  u16* WgT_l  = (u16*)(ws + o);  o += 1572864;
  u16* hWT_h  = (u16*)(ws + o);  o += 8388608;
  u16* hWT_l  = (u16*)(ws + o);  o += 8388608;
  u16* oWT_h  = (u16*)(ws + o);  o += 4194304;
  u16* oWT_l  = (u16*)(ws + o);  o += 4194304;
  float* h2T  = (float*)(ws + o); o += 16777216;
  float* esrc = (float*)(ws + o); o += 65536;
  float* edst = (float*)(ws + o); o += 65536;
  float* e2s  = (float*)(ws + o); o += 32768;
  float* e2d  = (float*)(ws + o); o += 32768;
  float* lgts = (float*)(ws + o); o += 32768;
  char* pool  = ws + o;          o += 81788928;   // chunk pool, reused by stage 2

  // chunk-pool carve (C = 16 batches per chunk)
  u16* hT_h   = (u16*)(pool + 0);          // 16.8 MB  (16*8*512 rows x 128)
  u16* hT_l   = (u16*)(pool + 16777216);
  u16* x1_h   = (u16*)(pool + 33554432);   // 16.8 MB  (2048 x 4096)
  u16* x1_l   = (u16*)(pool + 50331648);
  char* sub   = pool + 67108864;           // 14.7 MB: xoff+xw, att overlays
  u16* xoff_h = (u16*)(sub + 0);           // 3.1 MB   (2048 x 768)
  u16* xoff_l = (u16*)(sub + 3145728);
  u16* xw_h   = (u16*)(sub + 6291456);     // 4.2 MB   (2048 x 1024)
  u16* xw_l   = (u16*)(sub + 10485760);
  u16* att_h  = (u16*)(sub + 0);           // 4.2 MB   (overlays dead xoff)
  u16* att_l  = (u16*)(sub + 4194304);
  // stage-2 carve (pool reused after chunk loop)
  float* att2 = (float*)(pool + 0);        // 4.2 MB
  float* x2   = (float*)(pool + 4194304);  // 16.8 MB

  // weight packing (hi/lo split + transpose to BT layouts)
  pack_wgT<<<3072, 256, 0, stream>>>(Wg_w, WgT_h, WgT_l);
  pack_hwT<<<16384, 256, 0, stream>>>(hW_w, hWT_h, hWT_l);
  pack_owT<<<8192, 256, 0, stream>>>(oW_w, oWT_h, oWT_l);

  for (int b0 = 0; b0 < B_; b0 += CHUNK_) {
    // group pool -> x_off (split), ig
    group_pool_kernel<<<dim3(CHUNK_, 6), 128, 0, stream>>>(
        x + (size_t)b0 * 98304, offs + b0 * 256, xoff_h, xoff_l, ig + b0 * 256);

    // G2 (swapped): xw[node][feat] = x_off @ Wg + Wg_b. M=1024(feat),N=2048(node),K=768
    mfma_split_gemm<<<dim3(16, 8, 1), 256, 0, stream>>>(
        WgT_h, WgT_l, xoff_h, xoff_l, Wg_b, 2,
        xw_h, xw_l, nullptr, 0, 0, 768, 0, 0,
        10, 0, 13, 0, 1024, 0, 0, 1);

    // G3: hT[(bc*8+h)*512+o][i] = (xw @ hW + hW_b)^T. M=2048,N=4096,K=1024
    mfma_split_gemm<<<dim3(32, 16, 1), 256, 0, stream>>>(
        xw_h, xw_l, hWT_h, hWT_l, hW_b, 1,
        hT_h, hT_l, nullptr, 0, 0, 1024, 0, 0,
        7, 524288, 9, 65536, 128, 0, 0, 1);

    // attention-1 logits + softmax (split att for MFMA)
    dot_pairs_hT<<<CHUNK_ * 8, 128, 0, stream>>>(hT_h, hT_l, ha_w, esrc, edst);
    edge_softmax_kernel<<<CHUNK_ * 8 * 128, 64, 0, stream>>>(
        esrc, edst, ha_b, adj + (size_t)b0 * 16384, nullptr, att_h, att_l, 8, 1);

    // x1T (swapped): x1[bc*128+i][h*512+o] = elu(att @ h). per z=(bc,h):
    // M=512(o),N=128(i),K=128(j); A=hT slab, B=att slab.
    mfma_split_gemm<<<dim3(1, 4, CHUNK_ * 8), 256, 0, stream>>>(
        hT_h, hT_l, att_h, att_l, nullptr, 0,
        x1_h, x1_l, nullptr, 0, 1, 128, 65536, 16384,
        9, 0, 7, 0, 4096, 524288, 512, 8);

    // G7: h2T[o][b0*128+m] = (x1 @ oW + oW_b)^T. M=2048,N=512,K=4096, fp32 out
    mfma_split_gemm<<<dim3(4, 16, 1), 256, 0, stream>>>(
        x1_h, x1_l, oWT_h, oWT_l, oW_b, 1,
        nullptr, nullptr, h2T + b0 * 128, 1, 0, 4096, 0, 0,
        13, 0, 9, 0, 8192, 0, 0, 1);
  }

  // attention-2 (fp32, unchunked)
  dot_pairs_h2T<<<64, 128, 0, stream>>>(h2T, oa_w, e2s, e2d);
  edge_softmax_kernel<<<8192, 64, 0, stream>>>(e2s, e2d, oa_b, adj,
      att2, nullptr, nullptr, 1, 0);
  bgemm_elu_bt_f32<<<dim3(16, 64), 256, 0, stream>>>(att2, h2T, x2);

  // logits + finalize
  logits_kernel<<<2048, 256, 0, stream>>>(x2, fin_w, fin_b, lgts, 8192);
  finalize_kernel<<<B_, 128, 0, stream>>>(lgts, tag, amask, ig, out);
}

// Round 6
// 1322.734 us; speedup vs baseline: 1.7680x; 1.3823x over previous
//
#include <hip/hip_runtime.h>
#include <cstddef>
#include <cstdint>

#define B_ 64
#define N_ 128
#define FIN_ 768
#define NEG_E_ (-9.0e15f)
#define NEG_S_ (-9.0e10f)
#define CHUNK_ 16

typedef unsigned short u16;
typedef unsigned int u32;
typedef float f32x4 __attribute__((ext_vector_type(4)));
typedef short s16x8 __attribute__((ext_vector_type(8)));   // 8 bf16 frag
typedef u16 u16x4 __attribute__((ext_vector_type(4)));

__device__ __forceinline__ u16 f2bf(float x) {
  u32 u = __float_as_uint(x);
  return (u16)((u + 0x7fffu + ((u >> 16) & 1u)) >> 16);
}
__device__ __forceinline__ float b2f(u16 h) {
  return __uint_as_float(((u32)h) << 16);
}

// ---------------------------------------------------------------------------
// Group pooling -> x_off split bf16 (hi/lo) + index_group. Chunk-local b.
// ---------------------------------------------------------------------------
__global__ __launch_bounds__(128) void group_pool_kernel(
    const float* __restrict__ x, const int* __restrict__ offs,
    u16* __restrict__ xoh, u16* __restrict__ xol, int* __restrict__ ig)
{
  const int b = blockIdx.x;
  const int fc = blockIdx.y;
  const int tid = threadIdx.x;
  __shared__ int o0[N_], o1[N_];
  __shared__ int endk[N_ + 2];
  __shared__ int Gs;
  o0[tid] = offs[(b * N_ + tid) * 2 + 0];
  o1[tid] = offs[(b * N_ + tid) * 2 + 1];
  __syncthreads();
  if (tid == 0) {
    int fz = N_;
    for (int k = 0; k < N_; ++k) { if (o0[k] == 0 && o1[k] == 0) { fz = k; break; } }
    int g = 0;
    endk[0] = 0;
    for (int k = 0; k < fz; ++k) {
      int nxt = (k + 1 < N_) ? o0[k + 1] : 0;
      if (o1[k] == nxt - 1 && g < N_) { endk[g + 1] = k + 1; ++g; }
    }
    Gs = g;
  }
  __syncthreads();
  const int G = Gs;
  const int f = fc * 128 + tid;
  for (int g = 0; g < N_; ++g) {
    float v = 0.0f;
    if (g < G) {
      int s = endk[g], e = endk[g + 1];
      float acc = 0.0f;
      for (int k = s; k < e; ++k) acc += x[((size_t)b * N_ + k) * FIN_ + f];
      v = acc / (float)(e - s);
    }
    u16 hh = f2bf(v);
    size_t oo = ((size_t)b * N_ + g) * FIN_ + f;
    xoh[oo] = hh;
    xol[oo] = f2bf(v - b2f(hh));
  }
  if (fc == 0) {
    int g = tid;
    int s = (g < G) ? endk[g] : 0;
    int e = (g < G) ? endk[g + 1] : 0;
    ig[(b * N_ + g) * 2 + 0] = s;
    ig[(b * N_ + g) * 2 + 1] = e;
  }
}

// ---------------------------------------------------------------------------
// Weight pack/transpose/split kernels
// ---------------------------------------------------------------------------
__global__ __launch_bounds__(256) void pack_wgT(  // Wg_w[768][1024] -> WgT[1024][768]
    const float* __restrict__ w, u16* __restrict__ th, u16* __restrict__ tl)
{
  int idx = blockIdx.x * 256 + threadIdx.x;
  float v = w[idx];
  int k = idx >> 10, n = idx & 1023;
  u16 h = f2bf(v);
  th[n * 768 + k] = h;
  tl[n * 768 + k] = f2bf(v - b2f(h));
}
__global__ __launch_bounds__(256) void pack_hwT(  // hW_w[8][1024][512] -> hWT[4096][1024]
    const float* __restrict__ w, u16* __restrict__ th, u16* __restrict__ tl)
{
  int idx = blockIdx.x * 256 + threadIdx.x;
  float v = w[idx];
  int hd = idx >> 19, f = (idx >> 9) & 1023, o = idx & 511;
  int dst = (hd * 512 + o) * 1024 + f;
  u16 h = f2bf(v);
  th[dst] = h;
  tl[dst] = f2bf(v - b2f(h));
}
__global__ __launch_bounds__(256) void pack_owT(  // oW_w[4096][512] -> oWT[512][4096]
    const float* __restrict__ w, u16* __restrict__ th, u16* __restrict__ tl)
{
  int idx = blockIdx.x * 256 + threadIdx.x;
  float v = w[idx];
  int k = idx >> 9, o = idx & 511;
  int dst = o * 4096 + k;
  u16 h = f2bf(v);
  th[dst] = h;
  tl[dst] = f2bf(v - b2f(h));
}

// ---------------------------------------------------------------------------
// Split-bf16 MFMA GEMM with register-prefetch pipeline.
// C[m][n] = sum_k (Ah+Al)[m][k]*(Bh+Bl)[k][n] (3-term split product).
// A: row-major, row stride lda (hi/lo).  B: BT layout, row stride ldb (hi/lo).
// z indexes batch/slice: A base += z*Az, B base += z*Bz (element offsets).
// Output: off = (m>>msh)*s_mb + (m&mmask) + (n>>nsh)*s_nb + (n&nmask)*s_n
//   + (z/zH)*zb_s + (z%zH)*zh_s.   128x128 tile, 4 waves (2x2 of 64x64),
// per-wave 4x4 frags of 16x16x32.
// ---------------------------------------------------------------------------
__global__ __launch_bounds__(256) void mfma_split_gemm(
    const u16* __restrict__ Ah, const u16* __restrict__ Al,
    const u16* __restrict__ Bh, const u16* __restrict__ Bl,
    const float* __restrict__ bias, int bias_mode,   // 0 none, 1 per-n, 2 per-m
    u16* __restrict__ Oh, u16* __restrict__ Ol, float* __restrict__ Of,
    int out_f32, int do_elu,
    int K, int lda, int ldb,
    long long Az, long long Bz,
    int msh, long long s_mb, int nsh, long long s_nb, long long s_n,
    long long zb_s, long long zh_s, int zH)
{
  __shared__ u16 As_h[128][40];
  __shared__ u16 As_l[128][40];
  __shared__ u16 Bs_h[128][40];
  __shared__ u16 Bs_l[128][40];
  const int tid = threadIdx.x;
  const int wave = tid >> 6, lane = tid & 63;
  const int wm = (wave >> 1) * 64, wn = (wave & 1) * 64;
  const int bn = blockIdx.x * 128, bm = blockIdx.y * 128;
  const int z = blockIdx.z;
  const u16* Ahb = Ah + (long long)z * Az;
  const u16* Alb = Al + (long long)z * Az;
  const u16* Bhb = Bh + (long long)z * Bz;
  const u16* Blb = Bl + (long long)z * Bz;
  const int lm = lane & 15, lq = lane >> 4;

  // staging coords: thread covers row sr, u16 cols [sc, sc+16)
  const int sr = tid >> 1;
  const int sc = (tid & 1) * 16;
  const size_t ga = (size_t)(bm + sr) * lda + sc;
  const size_t gb = (size_t)(bn + sr) * ldb + sc;

  f32x4 acc[4][4];
#pragma unroll
  for (int i = 0; i < 4; ++i)
#pragma unroll
    for (int j = 0; j < 4; ++j) acc[i][j] = (f32x4){0.0f, 0.0f, 0.0f, 0.0f};

  uint4 r0, r1, r2, r3, r4, r5, r6, r7;
  // prologue: load iter 0
  r0 = *(const uint4*)(Ahb + ga);
  r1 = *(const uint4*)(Ahb + ga + 8);
  r2 = *(const uint4*)(Alb + ga);
  r3 = *(const uint4*)(Alb + ga + 8);
  r4 = *(const uint4*)(Bhb + gb);
  r5 = *(const uint4*)(Bhb + gb + 8);
  r6 = *(const uint4*)(Blb + gb);
  r7 = *(const uint4*)(Blb + gb + 8);

  for (int k0 = 0; k0 < K; k0 += 32) {
    __syncthreads();                    // all prior-iter LDS reads done
    *(uint4*)&As_h[sr][sc] = r0;
    *(uint4*)&As_h[sr][sc + 8] = r1;
    *(uint4*)&As_l[sr][sc] = r2;
    *(uint4*)&As_l[sr][sc + 8] = r3;
    *(uint4*)&Bs_h[sr][sc] = r4;
    *(uint4*)&Bs_h[sr][sc + 8] = r5;
    *(uint4*)&Bs_l[sr][sc] = r6;
    *(uint4*)&Bs_l[sr][sc + 8] = r7;
    __syncthreads();
    int kn = k0 + 32;
    if (kn < K) {                       // prefetch next iter (latency covered
      r0 = *(const uint4*)(Ahb + ga + kn);          // by ds_read + MFMA below)
      r1 = *(const uint4*)(Ahb + ga + kn + 8);
      r2 = *(const uint4*)(Alb + ga + kn);
      r3 = *(const uint4*)(Alb + ga + kn + 8);
      r4 = *(const uint4*)(Bhb + gb + kn);
      r5 = *(const uint4*)(Bhb + gb + kn + 8);
      r6 = *(const uint4*)(Blb + gb + kn);
      r7 = *(const uint4*)(Blb + gb + kn + 8);
    }
    s16x8 fa_h[4], fa_l[4], fb_h[4], fb_l[4];
#pragma unroll
    for (int t = 0; t < 4; ++t) {
      fa_h[t] = *(const s16x8*)&As_h[wm + t * 16 + lm][lq * 8];
      fa_l[t] = *(const s16x8*)&As_l[wm + t * 16 + lm][lq * 8];
      fb_h[t] = *(const s16x8*)&Bs_h[wn + t * 16 + lm][lq * 8];
      fb_l[t] = *(const s16x8*)&Bs_l[wn + t * 16 + lm][lq * 8];
    }
#pragma unroll
    for (int i = 0; i < 4; ++i)
#pragma unroll
      for (int j = 0; j < 4; ++j) {
        acc[i][j] = __builtin_amdgcn_mfma_f32_16x16x32_bf16(fa_h[i], fb_h[j], acc[i][j], 0, 0, 0);
        acc[i][j] = __builtin_amdgcn_mfma_f32_16x16x32_bf16(fa_h[i], fb_l[j], acc[i][j], 0, 0, 0);
        acc[i][j] = __builtin_amdgcn_mfma_f32_16x16x32_bf16(fa_l[i], fb_h[j], acc[i][j], 0, 0, 0);
      }
  }

  // epilogue: C row m = quad*4+reg (4 consecutive), col n = lane&15
  const long long zoff = (long long)(z / zH) * zb_s + (long long)(z % zH) * zh_s;
  const int mmask = (1 << msh) - 1;
  const int nmask = (1 << nsh) - 1;
#pragma unroll
  for (int i = 0; i < 4; ++i) {
    int mb = bm + wm + i * 16 + lq * 4;
#pragma unroll
    for (int j = 0; j < 4; ++j) {
      int n = bn + wn + j * 16 + lm;
      f32x4 v = acc[i][j];
      if (bias_mode == 1) {
        v += bias[n];
      } else if (bias_mode == 2) {
        f32x4 b4 = *(const f32x4*)&bias[mb];
        v += b4;
      }
      if (do_elu) {
        v.x = v.x > 0.0f ? v.x : expm1f(v.x);
        v.y = v.y > 0.0f ? v.y : expm1f(v.y);
        v.z = v.z > 0.0f ? v.z : expm1f(v.z);
        v.w = v.w > 0.0f ? v.w : expm1f(v.w);
      }
      long long off = (long long)(mb >> msh) * s_mb + (long long)(mb & mmask)
                    + (long long)(n >> nsh) * s_nb + (long long)(n & nmask) * s_n + zoff;
      if (out_f32) {
        *(f32x4*)(Of + off) = v;
      } else {
        u16 h0 = f2bf(v.x), h1 = f2bf(v.y), h2 = f2bf(v.z), h3 = f2bf(v.w);
        u16x4 hv = {h0, h1, h2, h3};
        u16x4 lv = {f2bf(v.x - b2f(h0)), f2bf(v.y - b2f(h1)),
                    f2bf(v.z - b2f(h2)), f2bf(v.w - b2f(h3))};
        *(u16x4*)(Oh + off) = hv;
        *(u16x4*)(Ol + off) = lv;
      }
    }
  }
}

// ---------------------------------------------------------------------------
// Split-K reduces.
// reduce2_split: xw[node][feat] = ps[0]+ps[1] + Wg_b[feat], split bf16 out.
// ---------------------------------------------------------------------------
__global__ __launch_bounds__(256) void reduce2_split(
    const float* __restrict__ ps, const float* __restrict__ bias,
    u16* __restrict__ oh, u16* __restrict__ ol)
{
  int base = (blockIdx.x * 256 + threadIdx.x) * 4;   // 2048*1024 elements
  int feat = base & 1023;
  f32x4 v = *(const f32x4*)(ps + base);
  v += *(const f32x4*)(ps + base + 2097152);
  v += *(const f32x4*)(bias + feat);
  u16 h0 = f2bf(v.x), h1 = f2bf(v.y), h2 = f2bf(v.z), h3 = f2bf(v.w);
  u16x4 hv = {h0, h1, h2, h3};
  u16x4 lv = {f2bf(v.x - b2f(h0)), f2bf(v.y - b2f(h1)),
              f2bf(v.z - b2f(h2)), f2bf(v.w - b2f(h3))};
  *(u16x4*)(oh + base) = hv;
  *(u16x4*)(ol + base) = lv;
}

// reduce4_bias: h2T[o][col0+m] = sum_{ks<4} ps[ks][o][m] + oW_b[o]  (fp32)
__global__ __launch_bounds__(256) void reduce4_bias(
    const float* __restrict__ ps, const float* __restrict__ bias,
    float* __restrict__ h2T, int col0)
{
  int base = (blockIdx.x * 256 + threadIdx.x) * 4;   // 512*2048 elements
  int o = base >> 11, m = base & 2047;
  f32x4 v = *(const f32x4*)(ps + base);
  v += *(const f32x4*)(ps + base + 1048576);
  v += *(const f32x4*)(ps + base + 2097152);
  v += *(const f32x4*)(ps + base + 3145728);
  v += bias[o];
  *(f32x4*)(h2T + (size_t)o * 8192 + col0 + m) = v;
}

// ---------------------------------------------------------------------------
// esrc/edst from hT (split bf16): one block per chunk-local (bc,head).
// ---------------------------------------------------------------------------
__global__ __launch_bounds__(128) void dot_pairs_hT(
    const u16* __restrict__ hTh, const u16* __restrict__ hTl,
    const float* __restrict__ W,   // ha_w [8][1024]
    float* __restrict__ esrc, float* __restrict__ edst)
{
  int bh = blockIdx.x;
  int head = bh & 7;
  int i = threadIdx.x;
  const u16* ph = hTh + (size_t)bh * 65536;
  const u16* pl = hTl + (size_t)bh * 65536;
  const float* w1 = W + head * 1024;
  float s1 = 0.0f, s2 = 0.0f;
  for (int o = 0; o < 512; ++o) {
    float hv = b2f(ph[o * 128 + i]) + b2f(pl[o * 128 + i]);
    s1 = fmaf(hv, w1[o], s1);
    s2 = fmaf(hv, w1[512 + o], s2);
  }
  esrc[bh * 128 + i] = s1;
  edst[bh * 128 + i] = s2;
}

// e2 dots from h2T (fp32): one block per b (global).
__global__ __launch_bounds__(128) void dot_pairs_h2T(
    const float* __restrict__ h2T, const float* __restrict__ oa,
    float* __restrict__ e2s, float* __restrict__ e2d)
{
  int b = blockIdx.x;
  int i = threadIdx.x;
  float s1 = 0.0f, s2 = 0.0f;
  for (int o = 0; o < 512; ++o) {
    float hv = h2T[(size_t)o * 8192 + b * 128 + i];
    s1 = fmaf(hv, oa[o], s1);
    s2 = fmaf(hv, oa[512 + o], s2);
  }
  e2s[b * 128 + i] = s1;
  e2d[b * 128 + i] = s2;
}

// ---------------------------------------------------------------------------
// Edge softmax; split=1 -> bf16 hi/lo output, else fp32.  adj pre-offset.
// ---------------------------------------------------------------------------
__global__ __launch_bounds__(64) void edge_softmax_kernel(
    const float* __restrict__ esrc, const float* __restrict__ edst,
    const float* __restrict__ bias, const float* __restrict__ adj,
    float* __restrict__ attf, u16* __restrict__ atth, u16* __restrict__ attl,
    int H, int split)
{
  int row = blockIdx.x;            // (b*H + hd)*128 + i  (b chunk-local)
  int lane = threadIdx.x;
  int i = row & 127;
  int bh = row >> 7;
  int hd = bh % H;
  int b = bh / H;
  float es = esrc[row] + bias[hd];
  const float* adjr = adj + ((size_t)b * N_ + i) * N_;
  const float* edr = edst + (size_t)bh * N_;
  float v[2];
#pragma unroll
  for (int t = 0; t < 2; ++t) {
    int j = lane + t * 64;
    float e = es + edr[j];
    e = (e >= 0.0f) ? e : 0.2f * e;
    v[t] = (adjr[j] > 0.0f) ? e : NEG_E_;
  }
  float mx = fmaxf(v[0], v[1]);
  for (int off = 32; off; off >>= 1) mx = fmaxf(mx, __shfl_xor(mx, off));
  float e0 = expf(v[0] - mx), e1 = expf(v[1] - mx);
  float sm = e0 + e1;
  for (int off = 32; off; off >>= 1) sm += __shfl_xor(sm, off);
  float inv = 1.0f / sm;
  float p0 = e0 * inv, p1 = e1 * inv;
  size_t base = (size_t)row * N_;
  if (split) {
    u16 h0 = f2bf(p0), h1 = f2bf(p1);
    atth[base + lane] = h0;
    attl[base + lane] = f2bf(p0 - b2f(h0));
    atth[base + lane + 64] = h1;
    attl[base + lane + 64] = f2bf(p1 - b2f(h1));
  } else {
    attf[base + lane] = p0;
    attf[base + lane + 64] = p1;
  }
}

// ---------------------------------------------------------------------------
// Stage-2 fp32 batched GEMM + ELU, B from transposed layout (h2T[512][8192]).
// x2[b,i,o] = elu(sum_j att2[b,i,j] * h2T[o][b*128+j]).  64x64 tiles, BK=16.
// ---------------------------------------------------------------------------
__global__ __launch_bounds__(256) void bgemm_elu_bt_f32(
    const float* __restrict__ A, const float* __restrict__ BT,
    float* __restrict__ C)
{
  __shared__ float As[16][64];
  __shared__ float Bs[16][68];
  const int tid = threadIdx.x;
  const int tm = blockIdx.x >> 3, tn = blockIdx.x & 7;
  const int bm = tm * 64, bn = tn * 64;
  const int b = blockIdx.y;
  const float* Ab = A + (size_t)b * 16384;
  const float* BTb = BT + (size_t)b * 128;
  const int ty = tid >> 4, tx = tid & 15;
  const int ar = tid >> 2, ac = (tid & 3) * 4;
  float acc[4][4];
#pragma unroll
  for (int i = 0; i < 4; ++i)
#pragma unroll
    for (int j = 0; j < 4; ++j) acc[i][j] = 0.0f;

  for (int k0 = 0; k0 < 128; k0 += 16) {
    float4 av = *(const float4*)(Ab + (size_t)(bm + ar) * 128 + k0 + ac);
    float4 bv = *(const float4*)(BTb + (size_t)(bn + ar) * 8192 + k0 + ac);
    __syncthreads();
    As[ac + 0][ar] = av.x; As[ac + 1][ar] = av.y; As[ac + 2][ar] = av.z; As[ac + 3][ar] = av.w;
    Bs[ac + 0][ar] = bv.x; Bs[ac + 1][ar] = bv.y; Bs[ac + 2][ar] = bv.z; Bs[ac + 3][ar] = bv.w;
    __syncthreads();
#pragma unroll
    for (int kk = 0; kk < 16; ++kk) {
      float a[4], bb[4];
      *(float4*)a  = *(const float4*)&As[kk][ty * 4];
      *(float4*)bb = *(const float4*)&Bs[kk][tx * 4];
#pragma unroll
      for (int i = 0; i < 4; ++i)
#pragma unroll
        for (int j = 0; j < 4; ++j)
          acc[i][j] = fmaf(a[i], bb[j], acc[i][j]);
    }
  }
#pragma unroll
  for (int i = 0; i < 4; ++i) {
    int row = b * 128 + bm + ty * 4 + i;
    float4 v;
    v.x = acc[i][0] > 0.0f ? acc[i][0] : expm1f(acc[i][0]);
    v.y = acc[i][1] > 0.0f ? acc[i][1] : expm1f(acc[i][1]);
    v.z = acc[i][2] > 0.0f ? acc[i][2] : expm1f(acc[i][2]);
    v.w = acc[i][3] > 0.0f ? acc[i][3] : expm1f(acc[i][3]);
    *(float4*)(C + (size_t)row * 512 + bn + tx * 4) = v;
  }
}

// ---------------------------------------------------------------------------
// logits = x2 @ fin_w + fin_b  (one wave per row)
// ---------------------------------------------------------------------------
__global__ __launch_bounds__(256) void logits_kernel(
    const float* __restrict__ X, const float* __restrict__ w,
    const float* __restrict__ bptr, float* __restrict__ out, int R)
{
  int wv = (blockIdx.x * 256 + threadIdx.x) >> 6;
  int lane = threadIdx.x & 63;
  if (wv >= R) return;
  const float* xr = X + (size_t)wv * 512;
  float s = 0.0f;
#pragma unroll
  for (int i = 0; i < 8; ++i) {
    int c = lane + i * 64;
    s = fmaf(xr[c], w[c], s);
  }
  for (int off = 32; off; off >>= 1) s += __shfl_down(s, off);
  if (lane == 0) out[wv] = s + bptr[0];
}

// ---------------------------------------------------------------------------
// Final: scores -> stable rank -> gather fix -> expand.
// ---------------------------------------------------------------------------
__global__ __launch_bounds__(128) void finalize_kernel(
    const float* __restrict__ logits, const float* __restrict__ tag,
    const float* __restrict__ amask, const int* __restrict__ ig,
    int* __restrict__ out)
{
  const int b = blockIdx.x, tid = threadIdx.x;
  __shared__ float red[N_];
  __shared__ float scs[N_];
  __shared__ int fs[N_], fe[N_], lens[N_], csum[N_];
  __shared__ int redi[N_];

  float lg = logits[b * N_ + tid];
  float tg = tag[b * N_ + tid];
  float am = amask[b * N_ + tid];
  float m = (tg > 0.0f) ? am : 0.0f;

  float in1 = (m > 0.0f) ? lg * m : NEG_S_;
  red[tid] = in1; __syncthreads();
  for (int s = 64; s > 0; s >>= 1) { if (tid < s) red[tid] = fmaxf(red[tid], red[tid + s]); __syncthreads(); }
  float M1 = red[0]; __syncthreads();
  float e1 = expf(in1 - M1);
  red[tid] = e1; __syncthreads();
  for (int s = 64; s > 0; s >>= 1) { if (tid < s) red[tid] += red[tid + s]; __syncthreads(); }
  float S1 = red[0]; __syncthreads();
  float sc = e1 / S1;

  red[tid] = m; __syncthreads();
  for (int s = 64; s > 0; s >>= 1) { if (tid < s) red[tid] += red[tid + s]; __syncthreads(); }
  float SM = red[0]; __syncthreads();

  float in2 = (m > 0.0f) ? ((float)(N_ - tid) / SM) * m : NEG_S_;
  red[tid] = in2; __syncthreads();
  for (int s = 64; s > 0; s >>= 1) { if (tid < s) red[tid] = fmaxf(red[tid], red[tid + s]); __syncthreads(); }
  float M2 = red[0]; __syncthreads();
  float e2 = expf(in2 - M2);
  red[tid] = e2; __syncthreads();
  for (int s = 64; s > 0; s >>= 1) { if (tid < s) red[tid] += red[tid + s]; __syncthreads(); }
  float S2 = red[0]; __syncthreads();
  float ii = e2 / S2;

  scs[tid] = sc + ii;
  __syncthreads();

  float si = scs[tid];
  int rank = 0;
  for (int j = 0; j < N_; ++j) {
    float sj = scs[j];
    rank += (sj > si) || (sj == si && j < tid);
  }
  fs[tid] = ig[(b * N_ + rank) * 2 + 0];
  fe[tid] = ig[(b * N_ + rank) * 2 + 1];
  __syncthreads();

  redi[tid] = (fs[tid] == 0 && fe[tid] == 0) ? tid : N_;
  __syncthreads();
  for (int s = 64; s > 0; s >>= 1) { if (tid < s) redi[tid] = min(redi[tid], redi[tid + s]); __syncthreads(); }
  int fz = redi[0]; __syncthreads();
  lens[tid] = (tid < fz) ? (fe[tid] - fs[tid]) : 0;
  __syncthreads();
  if (tid == 0) {
    int r = 0;
    for (int k = 0; k < N_; ++k) { r += lens[k]; csum[k] = r; }
  }
  __syncthreads();
  int total = csum[N_ - 1];
  int l = tid;
  int k = 0;
  while (k < N_ && csum[k] <= l) ++k;
  if (k > N_ - 1) k = N_ - 1;
  int val = fs[k] + (l - (csum[k] - lens[k]));
  out[b * N_ + l] = (l < total) ? val : l;
}

// ---------------------------------------------------------------------------
extern "C" void kernel_launch(void* const* d_in, const int* in_sizes, int n_in,
                              void* d_out, int out_size, void* d_ws, size_t ws_size,
                              hipStream_t stream)
{
  const float* x     = (const float*)d_in[0];
  const float* tag   = (const float*)d_in[1];
  const int*   offs  = (const int*)  d_in[2];
  const float* amask = (const float*)d_in[3];
  const float* adj   = (const float*)d_in[4];
  const float* Wg_w  = (const float*)d_in[5];
  const float* Wg_b  = (const float*)d_in[6];
  const float* hW_w  = (const float*)d_in[7];
  const float* hW_b  = (const float*)d_in[8];
  const float* ha_w  = (const float*)d_in[9];
  const float* ha_b  = (const float*)d_in[10];
  const float* oW_w  = (const float*)d_in[11];
  const float* oW_b  = (const float*)d_in[12];
  const float* oa_w  = (const float*)d_in[13];
  const float* oa_b  = (const float*)d_in[14];
  const float* fin_w = (const float*)d_in[15];
  const float* fin_b = (const float*)d_in[16];
  int* out = (int*)d_out;

  // ---- workspace: 138.1 MB.  Proven: ws_size >= 197.5 MB (R2 C=32 fit),
  // R5 passed at 121.3 MB. ----
  char* ws = (char*)d_ws;
  size_t o = 0;
  int* ig     = (int*)(ws + o);  o += 131072;
  u16* WgT_h  = (u16*)(ws + o);  o += 1572864;
  u16* WgT_l  = (u16*)(ws + o);  o += 1572864;
  u16* hWT_h  = (u16*)(ws + o);  o += 8388608;
  u16* hWT_l  = (u16*)(ws + o);  o += 8388608;
  u16* oWT_h  = (u16*)(ws + o);  o += 4194304;
  u16* oWT_l  = (u16*)(ws + o);  o += 4194304;
  float* h2T  = (float*)(ws + o); o += 16777216;
  float* esrc = (float*)(ws + o); o += 65536;
  float* edst = (float*)(ws + o); o += 65536;
  float* e2s  = (float*)(ws + o); o += 32768;
  float* e2d  = (float*)(ws + o); o += 32768;
  float* lgts = (float*)(ws + o); o += 32768;
  float* ps   = (float*)(ws + o); o += 16777216;  // split-K partials (G2/G7)
  char* pool  = ws + o;          o += 81788928;   // chunk pool, reused by stage 2

  // chunk-pool carve (C = 16 batches per chunk)
  u16* hT_h   = (u16*)(pool + 0);          // 16.8 MB  (16*8*512 rows x 128)
  u16* hT_l   = (u16*)(pool + 16777216);
  u16* x1_h   = (u16*)(pool + 33554432);   // 16.8 MB  (2048 x 4096)
  u16* x1_l   = (u16*)(pool + 50331648);
  char* sub   = pool + 67108864;           // 14.7 MB: xoff+xw, att overlays
  u16* xoff_h = (u16*)(sub + 0);           // 3.1 MB   (2048 x 768)
  u16* xoff_l = (u16*)(sub + 3145728);
  u16* xw_h   = (u16*)(sub + 6291456);     // 4.2 MB   (2048 x 1024)
  u16* xw_l   = (u16*)(sub + 10485760);
  u16* att_h  = (u16*)(sub + 0);           // 4.2 MB   (overlays dead xoff)
  u16* att_l  = (u16*)(sub + 4194304);
  // stage-2 carve (pool reused after chunk loop)
  float* att2 = (float*)(pool + 0);        // 4.2 MB
  float* x2   = (float*)(pool + 4194304);  // 16.8 MB

  // weight packing (hi/lo split + transpose to BT layouts)
  pack_wgT<<<3072, 256, 0, stream>>>(Wg_w, WgT_h, WgT_l);
  pack_hwT<<<16384, 256, 0, stream>>>(hW_w, hWT_h, hWT_l);
  pack_owT<<<8192, 256, 0, stream>>>(oW_w, oWT_h, oWT_l);

  for (int b0 = 0; b0 < B_; b0 += CHUNK_) {
    // group pool -> x_off (split), ig
    group_pool_kernel<<<dim3(CHUNK_, 6), 128, 0, stream>>>(
        x + (size_t)b0 * 98304, offs + b0 * 256, xoff_h, xoff_l, ig + b0 * 256);

    // G2 (swapped, split-K=2): ps[z][node][feat] partial of x_off @ Wg.
    // M=1024(feat),N=2048(node),K=384/slice
    mfma_split_gemm<<<dim3(16, 8, 2), 256, 0, stream>>>(
        WgT_h, WgT_l, xoff_h, xoff_l, nullptr, 0,
        nullptr, nullptr, ps, 1, 0,
        384, 768, 768, 384, 384,
        10, 0, 13, 0, 1024, 0, 2097152, 2);
    reduce2_split<<<2048, 256, 0, stream>>>(ps, Wg_b, xw_h, xw_l);

    // G3: hT[(bc*8+h)*512+o][i] = (xw @ hW + hW_b)^T. M=2048,N=4096,K=1024
    mfma_split_gemm<<<dim3(32, 16, 1), 256, 0, stream>>>(
        xw_h, xw_l, hWT_h, hWT_l, hW_b, 1,
        hT_h, hT_l, nullptr, 0, 0,
        1024, 1024, 1024, 0, 0,
        7, 524288, 9, 65536, 128, 0, 0, 1);

    // attention-1 logits + softmax (split att for MFMA)
    dot_pairs_hT<<<CHUNK_ * 8, 128, 0, stream>>>(hT_h, hT_l, ha_w, esrc, edst);
    edge_softmax_kernel<<<CHUNK_ * 8 * 128, 64, 0, stream>>>(
        esrc, edst, ha_b, adj + (size_t)b0 * 16384, nullptr, att_h, att_l, 8, 1);

    // x1T (swapped): x1[bc*128+i][h*512+o] = elu(att @ h). per z=(bc,h):
    // M=512(o),N=128(i),K=128(j); A=hT slab, B=att slab.
    mfma_split_gemm<<<dim3(1, 4, CHUNK_ * 8), 256, 0, stream>>>(
        hT_h, hT_l, att_h, att_l, nullptr, 0,
        x1_h, x1_l, nullptr, 0, 1,
        128, 128, 128, 65536, 16384,
        9, 0, 7, 0, 4096, 524288, 512, 8);

    // G7 (split-K=4): ps[z][o][m] partial of x1 @ oW. M=2048,N=512,K=1024/slice
    mfma_split_gemm<<<dim3(4, 16, 4), 256, 0, stream>>>(
        x1_h, x1_l, oWT_h, oWT_l, nullptr, 0,
        nullptr, nullptr, ps, 1, 0,
        1024, 4096, 4096, 1024, 1024,
        13, 0, 9, 0, 2048, 0, 1048576, 4);
    reduce4_bias<<<1024, 256, 0, stream>>>(ps, oW_b, h2T, b0 * 128);
  }

  // attention-2 (fp32, unchunked)
  dot_pairs_h2T<<<64, 128, 0, stream>>>(h2T, oa_w, e2s, e2d);
  edge_softmax_kernel<<<8192, 64, 0, stream>>>(e2s, e2d, oa_b, adj,
      att2, nullptr, nullptr, 1, 0);
  bgemm_elu_bt_f32<<<dim3(16, 64), 256, 0, stream>>>(att2, h2T, x2);

  // logits + finalize
  logits_kernel<<<2048, 256, 0, stream>>>(x2, fin_w, fin_b, lgts, 8192);
  finalize_kernel<<<B_, 128, 0, stream>>>(lgts, tag, amask, ig, out);
}

// Round 7
// 1121.262 us; speedup vs baseline: 2.0857x; 1.1797x over previous
//
#include <hip/hip_runtime.h>
#include <cstddef>
#include <cstdint>

#define B_ 64
#define N_ 128
#define FIN_ 768
#define NEG_E_ (-9.0e15f)
#define NEG_S_ (-9.0e10f)
#define CHUNK_ 16

typedef unsigned short u16;
typedef unsigned int u32;
typedef float f32x4 __attribute__((ext_vector_type(4)));
typedef short s16x8 __attribute__((ext_vector_type(8)));   // 8 bf16 frag
typedef u16 u16x4 __attribute__((ext_vector_type(4)));

__device__ __forceinline__ u16 f2bf(float x) {
  u32 u = __float_as_uint(x);
  return (u16)((u + 0x7fffu + ((u >> 16) & 1u)) >> 16);
}
__device__ __forceinline__ float b2f(u16 h) {
  return __uint_as_float(((u32)h) << 16);
}

// ---------------------------------------------------------------------------
// Group pooling, k-sequential scan form: groups tile [0, endk[G]) contiguously
// so a running sum reset at LDS-precomputed boundaries computes all means in
// one static 128-iteration k-loop (unroll 8 -> 8 loads in flight).
// ---------------------------------------------------------------------------
__global__ __launch_bounds__(128) void group_pool_kernel(
    const float* __restrict__ x, const int* __restrict__ offs,
    u16* __restrict__ xoh, u16* __restrict__ xol, int* __restrict__ ig)
{
  const int b = blockIdx.x;
  const int fc = blockIdx.y;
  const int tid = threadIdx.x;
  __shared__ int o0[N_], o1[N_];
  __shared__ int bnd[N_];        // group index ending at k, else -1
  __shared__ float invlen[N_];
  __shared__ int st[N_], en[N_];
  __shared__ int Gs;
  o0[tid] = offs[(b * N_ + tid) * 2 + 0];
  o1[tid] = offs[(b * N_ + tid) * 2 + 1];
  bnd[tid] = -1;
  __syncthreads();
  if (tid == 0) {
    int fz = N_;
    for (int k = 0; k < N_; ++k) { if (o0[k] == 0 && o1[k] == 0) { fz = k; break; } }
    int g = 0, prev = 0;
    for (int k = 0; k < fz; ++k) {
      int nxt = (k + 1 < N_) ? o0[k + 1] : 0;
      if (o1[k] == nxt - 1 && g < N_) {
        bnd[k] = g;
        invlen[g] = 1.0f / (float)(k + 1 - prev);
        st[g] = prev;
        en[g] = k + 1;
        prev = k + 1;
        ++g;
      }
    }
    Gs = g;
  }
  __syncthreads();
  const int G = Gs;
  const int f = fc * 128 + tid;
  const float* xb = x + (size_t)b * N_ * FIN_ + f;
  float acc = 0.0f;
  for (int k0 = 0; k0 < N_; k0 += 8) {
    float v[8];
#pragma unroll
    for (int u = 0; u < 8; ++u) v[u] = xb[(size_t)(k0 + u) * FIN_];
#pragma unroll
    for (int u = 0; u < 8; ++u) {
      acc += v[u];
      int g = bnd[k0 + u];              // wave-uniform branch
      if (g >= 0) {
        float mean = acc * invlen[g];
        u16 hh = f2bf(mean);
        size_t oo = ((size_t)b * N_ + g) * FIN_ + f;
        xoh[oo] = hh;
        xol[oo] = f2bf(mean - b2f(hh));
        acc = 0.0f;
      }
    }
  }
  for (int g = G; g < N_; ++g) {
    size_t oo = ((size_t)b * N_ + g) * FIN_ + f;
    xoh[oo] = 0;
    xol[oo] = 0;
  }
  if (fc == 0) {
    int g = tid;
    ig[(b * N_ + g) * 2 + 0] = (g < G) ? st[g] : 0;
    ig[(b * N_ + g) * 2 + 1] = (g < G) ? en[g] : 0;
  }
}

// ---------------------------------------------------------------------------
// Weight pack/transpose/split kernels
// ---------------------------------------------------------------------------
__global__ __launch_bounds__(256) void pack_wgT(  // Wg_w[768][1024] -> WgT[1024][768]
    const float* __restrict__ w, u16* __restrict__ th, u16* __restrict__ tl)
{
  int idx = blockIdx.x * 256 + threadIdx.x;
  float v = w[idx];
  int k = idx >> 10, n = idx & 1023;
  u16 h = f2bf(v);
  th[n * 768 + k] = h;
  tl[n * 768 + k] = f2bf(v - b2f(h));
}
__global__ __launch_bounds__(256) void pack_hwT(  // hW_w[8][1024][512] -> hWT[4096][1024]
    const float* __restrict__ w, u16* __restrict__ th, u16* __restrict__ tl)
{
  int idx = blockIdx.x * 256 + threadIdx.x;
  float v = w[idx];
  int hd = idx >> 19, f = (idx >> 9) & 1023, o = idx & 511;
  int dst = (hd * 512 + o) * 1024 + f;
  u16 h = f2bf(v);
  th[dst] = h;
  tl[dst] = f2bf(v - b2f(h));
}
__global__ __launch_bounds__(256) void pack_owT(  // oW_w[4096][512] -> oWT[512][4096]
    const float* __restrict__ w, u16* __restrict__ th, u16* __restrict__ tl)
{
  int idx = blockIdx.x * 256 + threadIdx.x;
  float v = w[idx];
  int k = idx >> 9, o = idx & 511;
  int dst = o * 4096 + k;
  u16 h = f2bf(v);
  th[dst] = h;
  tl[dst] = f2bf(v - b2f(h));
}

// ---------------------------------------------------------------------------
// Split-bf16 MFMA GEMM with register-prefetch pipeline.
// (unchanged from round 6 -- see comments there)
// ---------------------------------------------------------------------------
__global__ __launch_bounds__(256) void mfma_split_gemm(
    const u16* __restrict__ Ah, const u16* __restrict__ Al,
    const u16* __restrict__ Bh, const u16* __restrict__ Bl,
    const float* __restrict__ bias, int bias_mode,   // 0 none, 1 per-n, 2 per-m
    u16* __restrict__ Oh, u16* __restrict__ Ol, float* __restrict__ Of,
    int out_f32, int do_elu,
    int K, int lda, int ldb,
    long long Az, long long Bz,
    int msh, long long s_mb, int nsh, long long s_nb, long long s_n,
    long long zb_s, long long zh_s, int zH)
{
  __shared__ u16 As_h[128][40];
  __shared__ u16 As_l[128][40];
  __shared__ u16 Bs_h[128][40];
  __shared__ u16 Bs_l[128][40];
  const int tid = threadIdx.x;
  const int wave = tid >> 6, lane = tid & 63;
  const int wm = (wave >> 1) * 64, wn = (wave & 1) * 64;
  const int bn = blockIdx.x * 128, bm = blockIdx.y * 128;
  const int z = blockIdx.z;
  const u16* Ahb = Ah + (long long)z * Az;
  const u16* Alb = Al + (long long)z * Az;
  const u16* Bhb = Bh + (long long)z * Bz;
  const u16* Blb = Bl + (long long)z * Bz;
  const int lm = lane & 15, lq = lane >> 4;

  const int sr = tid >> 1;
  const int sc = (tid & 1) * 16;
  const size_t ga = (size_t)(bm + sr) * lda + sc;
  const size_t gb = (size_t)(bn + sr) * ldb + sc;

  f32x4 acc[4][4];
#pragma unroll
  for (int i = 0; i < 4; ++i)
#pragma unroll
    for (int j = 0; j < 4; ++j) acc[i][j] = (f32x4){0.0f, 0.0f, 0.0f, 0.0f};

  uint4 r0, r1, r2, r3, r4, r5, r6, r7;
  r0 = *(const uint4*)(Ahb + ga);
  r1 = *(const uint4*)(Ahb + ga + 8);
  r2 = *(const uint4*)(Alb + ga);
  r3 = *(const uint4*)(Alb + ga + 8);
  r4 = *(const uint4*)(Bhb + gb);
  r5 = *(const uint4*)(Bhb + gb + 8);
  r6 = *(const uint4*)(Blb + gb);
  r7 = *(const uint4*)(Blb + gb + 8);

  for (int k0 = 0; k0 < K; k0 += 32) {
    __syncthreads();
    *(uint4*)&As_h[sr][sc] = r0;
    *(uint4*)&As_h[sr][sc + 8] = r1;
    *(uint4*)&As_l[sr][sc] = r2;
    *(uint4*)&As_l[sr][sc + 8] = r3;
    *(uint4*)&Bs_h[sr][sc] = r4;
    *(uint4*)&Bs_h[sr][sc + 8] = r5;
    *(uint4*)&Bs_l[sr][sc] = r6;
    *(uint4*)&Bs_l[sr][sc + 8] = r7;
    __syncthreads();
    int kn = k0 + 32;
    if (kn < K) {
      r0 = *(const uint4*)(Ahb + ga + kn);
      r1 = *(const uint4*)(Ahb + ga + kn + 8);
      r2 = *(const uint4*)(Alb + ga + kn);
      r3 = *(const uint4*)(Alb + ga + kn + 8);
      r4 = *(const uint4*)(Bhb + gb + kn);
      r5 = *(const uint4*)(Bhb + gb + kn + 8);
      r6 = *(const uint4*)(Blb + gb + kn);
      r7 = *(const uint4*)(Blb + gb + kn + 8);
    }
    s16x8 fa_h[4], fa_l[4], fb_h[4], fb_l[4];
#pragma unroll
    for (int t = 0; t < 4; ++t) {
      fa_h[t] = *(const s16x8*)&As_h[wm + t * 16 + lm][lq * 8];
      fa_l[t] = *(const s16x8*)&As_l[wm + t * 16 + lm][lq * 8];
      fb_h[t] = *(const s16x8*)&Bs_h[wn + t * 16 + lm][lq * 8];
      fb_l[t] = *(const s16x8*)&Bs_l[wn + t * 16 + lm][lq * 8];
    }
#pragma unroll
    for (int i = 0; i < 4; ++i)
#pragma unroll
      for (int j = 0; j < 4; ++j) {
        acc[i][j] = __builtin_amdgcn_mfma_f32_16x16x32_bf16(fa_h[i], fb_h[j], acc[i][j], 0, 0, 0);
        acc[i][j] = __builtin_amdgcn_mfma_f32_16x16x32_bf16(fa_h[i], fb_l[j], acc[i][j], 0, 0, 0);
        acc[i][j] = __builtin_amdgcn_mfma_f32_16x16x32_bf16(fa_l[i], fb_h[j], acc[i][j], 0, 0, 0);
      }
  }

  const long long zoff = (long long)(z / zH) * zb_s + (long long)(z % zH) * zh_s;
  const int mmask = (1 << msh) - 1;
  const int nmask = (1 << nsh) - 1;
#pragma unroll
  for (int i = 0; i < 4; ++i) {
    int mb = bm + wm + i * 16 + lq * 4;
#pragma unroll
    for (int j = 0; j < 4; ++j) {
      int n = bn + wn + j * 16 + lm;
      f32x4 v = acc[i][j];
      if (bias_mode == 1) {
        v += bias[n];
      } else if (bias_mode == 2) {
        f32x4 b4 = *(const f32x4*)&bias[mb];
        v += b4;
      }
      if (do_elu) {
        v.x = v.x > 0.0f ? v.x : expm1f(v.x);
        v.y = v.y > 0.0f ? v.y : expm1f(v.y);
        v.z = v.z > 0.0f ? v.z : expm1f(v.z);
        v.w = v.w > 0.0f ? v.w : expm1f(v.w);
      }
      long long off = (long long)(mb >> msh) * s_mb + (long long)(mb & mmask)
                    + (long long)(n >> nsh) * s_nb + (long long)(n & nmask) * s_n + zoff;
      if (out_f32) {
        *(f32x4*)(Of + off) = v;
      } else {
        u16 h0 = f2bf(v.x), h1 = f2bf(v.y), h2 = f2bf(v.z), h3 = f2bf(v.w);
        u16x4 hv = {h0, h1, h2, h3};
        u16x4 lv = {f2bf(v.x - b2f(h0)), f2bf(v.y - b2f(h1)),
                    f2bf(v.z - b2f(h2)), f2bf(v.w - b2f(h3))};
        *(u16x4*)(Oh + off) = hv;
        *(u16x4*)(Ol + off) = lv;
      }
    }
  }
}

// ---------------------------------------------------------------------------
// Split-K reduces.
// ---------------------------------------------------------------------------
__global__ __launch_bounds__(256) void reduce2_split(
    const float* __restrict__ ps, const float* __restrict__ bias,
    u16* __restrict__ oh, u16* __restrict__ ol)
{
  int base = (blockIdx.x * 256 + threadIdx.x) * 4;   // 2048*1024 elements
  int feat = base & 1023;
  f32x4 v = *(const f32x4*)(ps + base);
  v += *(const f32x4*)(ps + base + 2097152);
  v += *(const f32x4*)(bias + feat);
  u16 h0 = f2bf(v.x), h1 = f2bf(v.y), h2 = f2bf(v.z), h3 = f2bf(v.w);
  u16x4 hv = {h0, h1, h2, h3};
  u16x4 lv = {f2bf(v.x - b2f(h0)), f2bf(v.y - b2f(h1)),
              f2bf(v.z - b2f(h2)), f2bf(v.w - b2f(h3))};
  *(u16x4*)(oh + base) = hv;
  *(u16x4*)(ol + base) = lv;
}

__global__ __launch_bounds__(256) void reduce4_bias(
    const float* __restrict__ ps, const float* __restrict__ bias,
    float* __restrict__ h2T, int col0)
{
  int base = (blockIdx.x * 256 + threadIdx.x) * 4;   // 512*2048 elements
  int o = base >> 11, m = base & 2047;
  f32x4 v = *(const f32x4*)(ps + base);
  v += *(const f32x4*)(ps + base + 1048576);
  v += *(const f32x4*)(ps + base + 2097152);
  v += *(const f32x4*)(ps + base + 3145728);
  v += bias[o];
  *(f32x4*)(h2T + (size_t)o * 8192 + col0 + m) = v;
}

// ---------------------------------------------------------------------------
// esrc/edst from hT (split bf16): block per (bc,head), 512 threads =
// 4 o-partitions x 128 nodes; unroll-8 inner loop; LDS partial reduce.
// ---------------------------------------------------------------------------
__global__ __launch_bounds__(512) void dot_pairs_hT(
    const u16* __restrict__ hTh, const u16* __restrict__ hTl,
    const float* __restrict__ W,   // ha_w [8][1024]
    float* __restrict__ esrc, float* __restrict__ edst)
{
  int bh = blockIdx.x;
  int head = bh & 7;
  int tid = threadIdx.x;
  int os = tid >> 7, i = tid & 127;
  const u16* ph = hTh + (size_t)bh * 65536 + (size_t)os * 16384 + i;
  const u16* pl = hTl + (size_t)bh * 65536 + (size_t)os * 16384 + i;
  const float* w1 = W + head * 1024 + os * 128;
  float s1 = 0.0f, s2 = 0.0f;
#pragma unroll 8
  for (int o = 0; o < 128; ++o) {
    float hv = b2f(ph[o * 128]) + b2f(pl[o * 128]);
    s1 = fmaf(hv, w1[o], s1);
    s2 = fmaf(hv, w1[512 + o], s2);
  }
  __shared__ float sh1[4][128], sh2[4][128];
  sh1[os][i] = s1;
  sh2[os][i] = s2;
  __syncthreads();
  if (os == 0) {
    esrc[bh * 128 + i] = sh1[0][i] + sh1[1][i] + sh1[2][i] + sh1[3][i];
    edst[bh * 128 + i] = sh2[0][i] + sh2[1][i] + sh2[2][i] + sh2[3][i];
  }
}

// e2 dots from h2T (fp32): block per b, 512 threads (4 o-parts x 128 nodes).
__global__ __launch_bounds__(512) void dot_pairs_h2T(
    const float* __restrict__ h2T, const float* __restrict__ oa,
    float* __restrict__ e2s, float* __restrict__ e2d)
{
  int b = blockIdx.x;
  int tid = threadIdx.x;
  int os = tid >> 7, i = tid & 127;
  const float* hb = h2T + (size_t)os * 128 * 8192 + b * 128 + i;
  const float* oa1 = oa + os * 128;
  float s1 = 0.0f, s2 = 0.0f;
#pragma unroll 8
  for (int o = 0; o < 128; ++o) {
    float hv = hb[(size_t)o * 8192];
    s1 = fmaf(hv, oa1[o], s1);
    s2 = fmaf(hv, oa1[512 + o], s2);
  }
  __shared__ float sh1[4][128], sh2[4][128];
  sh1[os][i] = s1;
  sh2[os][i] = s2;
  __syncthreads();
  if (os == 0) {
    e2s[b * 128 + i] = sh1[0][i] + sh1[1][i] + sh1[2][i] + sh1[3][i];
    e2d[b * 128 + i] = sh2[0][i] + sh2[1][i] + sh2[2][i] + sh2[3][i];
  }
}

// ---------------------------------------------------------------------------
// Edge softmax; split=1 -> bf16 hi/lo output, else fp32.  adj pre-offset.
// ---------------------------------------------------------------------------
__global__ __launch_bounds__(64) void edge_softmax_kernel(
    const float* __restrict__ esrc, const float* __restrict__ edst,
    const float* __restrict__ bias, const float* __restrict__ adj,
    float* __restrict__ attf, u16* __restrict__ atth, u16* __restrict__ attl,
    int H, int split)
{
  int row = blockIdx.x;            // (b*H + hd)*128 + i  (b chunk-local)
  int lane = threadIdx.x;
  int i = row & 127;
  int bh = row >> 7;
  int hd = bh % H;
  int b = bh / H;
  float es = esrc[row] + bias[hd];
  const float* adjr = adj + ((size_t)b * N_ + i) * N_;
  const float* edr = edst + (size_t)bh * N_;
  float v[2];
#pragma unroll
  for (int t = 0; t < 2; ++t) {
    int j = lane + t * 64;
    float e = es + edr[j];
    e = (e >= 0.0f) ? e : 0.2f * e;
    v[t] = (adjr[j] > 0.0f) ? e : NEG_E_;
  }
  float mx = fmaxf(v[0], v[1]);
  for (int off = 32; off; off >>= 1) mx = fmaxf(mx, __shfl_xor(mx, off));
  float e0 = expf(v[0] - mx), e1 = expf(v[1] - mx);
  float sm = e0 + e1;
  for (int off = 32; off; off >>= 1) sm += __shfl_xor(sm, off);
  float inv = 1.0f / sm;
  float p0 = e0 * inv, p1 = e1 * inv;
  size_t base = (size_t)row * N_;
  if (split) {
    u16 h0 = f2bf(p0), h1 = f2bf(p1);
    atth[base + lane] = h0;
    attl[base + lane] = f2bf(p0 - b2f(h0));
    atth[base + lane + 64] = h1;
    attl[base + lane + 64] = f2bf(p1 - b2f(h1));
  } else {
    attf[base + lane] = p0;
    attf[base + lane + 64] = p1;
  }
}

// ---------------------------------------------------------------------------
// Stage-2 fp32 batched GEMM + ELU, B from transposed layout (h2T[512][8192]).
// ---------------------------------------------------------------------------
__global__ __launch_bounds__(256) void bgemm_elu_bt_f32(
    const float* __restrict__ A, const float* __restrict__ BT,
    float* __restrict__ C)
{
  __shared__ float As[16][64];
  __shared__ float Bs[16][68];
  const int tid = threadIdx.x;
  const int tm = blockIdx.x >> 3, tn = blockIdx.x & 7;
  const int bm = tm * 64, bn = tn * 64;
  const int b = blockIdx.y;
  const float* Ab = A + (size_t)b * 16384;
  const float* BTb = BT + (size_t)b * 128;
  const int ty = tid >> 4, tx = tid & 15;
  const int ar = tid >> 2, ac = (tid & 3) * 4;
  float acc[4][4];
#pragma unroll
  for (int i = 0; i < 4; ++i)
#pragma unroll
    for (int j = 0; j < 4; ++j) acc[i][j] = 0.0f;

  for (int k0 = 0; k0 < 128; k0 += 16) {
    float4 av = *(const float4*)(Ab + (size_t)(bm + ar) * 128 + k0 + ac);
    float4 bv = *(const float4*)(BTb + (size_t)(bn + ar) * 8192 + k0 + ac);
    __syncthreads();
    As[ac + 0][ar] = av.x; As[ac + 1][ar] = av.y; As[ac + 2][ar] = av.z; As[ac + 3][ar] = av.w;
    Bs[ac + 0][ar] = bv.x; Bs[ac + 1][ar] = bv.y; Bs[ac + 2][ar] = bv.z; Bs[ac + 3][ar] = bv.w;
    __syncthreads();
#pragma unroll
    for (int kk = 0; kk < 16; ++kk) {
      float a[4], bb[4];
      *(float4*)a  = *(const float4*)&As[kk][ty * 4];
      *(float4*)bb = *(const float4*)&Bs[kk][tx * 4];
#pragma unroll
      for (int i = 0; i < 4; ++i)
#pragma unroll
        for (int j = 0; j < 4; ++j)
          acc[i][j] = fmaf(a[i], bb[j], acc[i][j]);
    }
  }
#pragma unroll
  for (int i = 0; i < 4; ++i) {
    int row = b * 128 + bm + ty * 4 + i;
    float4 v;
    v.x = acc[i][0] > 0.0f ? acc[i][0] : expm1f(acc[i][0]);
    v.y = acc[i][1] > 0.0f ? acc[i][1] : expm1f(acc[i][1]);
    v.z = acc[i][2] > 0.0f ? acc[i][2] : expm1f(acc[i][2]);
    v.w = acc[i][3] > 0.0f ? acc[i][3] : expm1f(acc[i][3]);
    *(float4*)(C + (size_t)row * 512 + bn + tx * 4) = v;
  }
}

// ---------------------------------------------------------------------------
// logits = x2 @ fin_w + fin_b  (one wave per row)
// ---------------------------------------------------------------------------
__global__ __launch_bounds__(256) void logits_kernel(
    const float* __restrict__ X, const float* __restrict__ w,
    const float* __restrict__ bptr, float* __restrict__ out, int R)
{
  int wv = (blockIdx.x * 256 + threadIdx.x) >> 6;
  int lane = threadIdx.x & 63;
  if (wv >= R) return;
  const float* xr = X + (size_t)wv * 512;
  float s = 0.0f;
#pragma unroll
  for (int i = 0; i < 8; ++i) {
    int c = lane + i * 64;
    s = fmaf(xr[c], w[c], s);
  }
  for (int off = 32; off; off >>= 1) s += __shfl_down(s, off);
  if (lane == 0) out[wv] = s + bptr[0];
}

// ---------------------------------------------------------------------------
// Final: scores -> stable rank -> gather fix -> expand.
// ---------------------------------------------------------------------------
__global__ __launch_bounds__(128) void finalize_kernel(
    const float* __restrict__ logits, const float* __restrict__ tag,
    const float* __restrict__ amask, const int* __restrict__ ig,
    int* __restrict__ out)
{
  const int b = blockIdx.x, tid = threadIdx.x;
  __shared__ float red[N_];
  __shared__ float scs[N_];
  __shared__ int fs[N_], fe[N_], lens[N_], csum[N_];
  __shared__ int redi[N_];

  float lg = logits[b * N_ + tid];
  float tg = tag[b * N_ + tid];
  float am = amask[b * N_ + tid];
  float m = (tg > 0.0f) ? am : 0.0f;

  float in1 = (m > 0.0f) ? lg * m : NEG_S_;
  red[tid] = in1; __syncthreads();
  for (int s = 64; s > 0; s >>= 1) { if (tid < s) red[tid] = fmaxf(red[tid], red[tid + s]); __syncthreads(); }
  float M1 = red[0]; __syncthreads();
  float e1 = expf(in1 - M1);
  red[tid] = e1; __syncthreads();
  for (int s = 64; s > 0; s >>= 1) { if (tid < s) red[tid] += red[tid + s]; __syncthreads(); }
  float S1 = red[0]; __syncthreads();
  float sc = e1 / S1;

  red[tid] = m; __syncthreads();
  for (int s = 64; s > 0; s >>= 1) { if (tid < s) red[tid] += red[tid + s]; __syncthreads(); }
  float SM = red[0]; __syncthreads();

  float in2 = (m > 0.0f) ? ((float)(N_ - tid) / SM) * m : NEG_S_;
  red[tid] = in2; __syncthreads();
  for (int s = 64; s > 0; s >>= 1) { if (tid < s) red[tid] = fmaxf(red[tid], red[tid + s]); __syncthreads(); }
  float M2 = red[0]; __syncthreads();
  float e2 = expf(in2 - M2);
  red[tid] = e2; __syncthreads();
  for (int s = 64; s > 0; s >>= 1) { if (tid < s) red[tid] += red[tid + s]; __syncthreads(); }
  float S2 = red[0]; __syncthreads();
  float ii = e2 / S2;

  scs[tid] = sc + ii;
  __syncthreads();

  float si = scs[tid];
  int rank = 0;
  for (int j = 0; j < N_; ++j) {
    float sj = scs[j];
    rank += (sj > si) || (sj == si && j < tid);
  }
  fs[tid] = ig[(b * N_ + rank) * 2 + 0];
  fe[tid] = ig[(b * N_ + rank) * 2 + 1];
  __syncthreads();

  redi[tid] = (fs[tid] == 0 && fe[tid] == 0) ? tid : N_;
  __syncthreads();
  for (int s = 64; s > 0; s >>= 1) { if (tid < s) redi[tid] = min(redi[tid], redi[tid + s]); __syncthreads(); }
  int fz = redi[0]; __syncthreads();
  lens[tid] = (tid < fz) ? (fe[tid] - fs[tid]) : 0;
  __syncthreads();
  if (tid == 0) {
    int r = 0;
    for (int k = 0; k < N_; ++k) { r += lens[k]; csum[k] = r; }
  }
  __syncthreads();
  int total = csum[N_ - 1];
  int l = tid;
  int k = 0;
  while (k < N_ && csum[k] <= l) ++k;
  if (k > N_ - 1) k = N_ - 1;
  int val = fs[k] + (l - (csum[k] - lens[k]));
  out[b * N_ + l] = (l < total) ? val : l;
}

// ---------------------------------------------------------------------------
extern "C" void kernel_launch(void* const* d_in, const int* in_sizes, int n_in,
                              void* d_out, int out_size, void* d_ws, size_t ws_size,
                              hipStream_t stream)
{
  const float* x     = (const float*)d_in[0];
  const float* tag   = (const float*)d_in[1];
  const int*   offs  = (const int*)  d_in[2];
  const float* amask = (const float*)d_in[3];
  const float* adj   = (const float*)d_in[4];
  const float* Wg_w  = (const float*)d_in[5];
  const float* Wg_b  = (const float*)d_in[6];
  const float* hW_w  = (const float*)d_in[7];
  const float* hW_b  = (const float*)d_in[8];
  const float* ha_w  = (const float*)d_in[9];
  const float* ha_b  = (const float*)d_in[10];
  const float* oW_w  = (const float*)d_in[11];
  const float* oW_b  = (const float*)d_in[12];
  const float* oa_w  = (const float*)d_in[13];
  const float* oa_b  = (const float*)d_in[14];
  const float* fin_w = (const float*)d_in[15];
  const float* fin_b = (const float*)d_in[16];
  int* out = (int*)d_out;

  // ---- workspace: 138.1 MB (proven safe: R6 passed at this layout) ----
  char* ws = (char*)d_ws;
  size_t o = 0;
  int* ig     = (int*)(ws + o);  o += 131072;
  u16* WgT_h  = (u16*)(ws + o);  o += 1572864;
  u16* WgT_l  = (u16*)(ws + o);  o += 1572864;
  u16* hWT_h  = (u16*)(ws + o);  o += 8388608;
  u16* hWT_l  = (u16*)(ws + o);  o += 8388608;
  u16* oWT_h  = (u16*)(ws + o);  o += 4194304;
  u16* oWT_l  = (u16*)(ws + o);  o += 4194304;
  float* h2T  = (float*)(ws + o); o += 16777216;
  float* esrc = (float*)(ws + o); o += 65536;
  float* edst = (float*)(ws + o); o += 65536;
  float* e2s  = (float*)(ws + o); o += 32768;
  float* e2d  = (float*)(ws + o); o += 32768;
  float* lgts = (float*)(ws + o); o += 32768;
  float* ps   = (float*)(ws + o); o += 16777216;  // split-K partials (G2/G7)
  char* pool  = ws + o;          o += 81788928;   // chunk pool, reused by stage 2

  u16* hT_h   = (u16*)(pool + 0);          // 16.8 MB
  u16* hT_l   = (u16*)(pool + 16777216);
  u16* x1_h   = (u16*)(pool + 33554432);   // 16.8 MB
  u16* x1_l   = (u16*)(pool + 50331648);
  char* sub   = pool + 67108864;           // 14.7 MB: xoff+xw, att overlays
  u16* xoff_h = (u16*)(sub + 0);
  u16* xoff_l = (u16*)(sub + 3145728);
  u16* xw_h   = (u16*)(sub + 6291456);
  u16* xw_l   = (u16*)(sub + 10485760);
  u16* att_h  = (u16*)(sub + 0);
  u16* att_l  = (u16*)(sub + 4194304);
  float* att2 = (float*)(pool + 0);
  float* x2   = (float*)(pool + 4194304);

  // weight packing (hi/lo split + transpose to BT layouts)
  pack_wgT<<<3072, 256, 0, stream>>>(Wg_w, WgT_h, WgT_l);
  pack_hwT<<<16384, 256, 0, stream>>>(hW_w, hWT_h, hWT_l);
  pack_owT<<<8192, 256, 0, stream>>>(oW_w, oWT_h, oWT_l);

  for (int b0 = 0; b0 < B_; b0 += CHUNK_) {
    group_pool_kernel<<<dim3(CHUNK_, 6), 128, 0, stream>>>(
        x + (size_t)b0 * 98304, offs + b0 * 256, xoff_h, xoff_l, ig + b0 * 256);

    // G2 (swapped, split-K=2): M=1024(feat),N=2048(node),K=384/slice
    mfma_split_gemm<<<dim3(16, 8, 2), 256, 0, stream>>>(
        WgT_h, WgT_l, xoff_h, xoff_l, nullptr, 0,
        nullptr, nullptr, ps, 1, 0,
        384, 768, 768, 384, 384,
        10, 0, 13, 0, 1024, 0, 2097152, 2);
    reduce2_split<<<2048, 256, 0, stream>>>(ps, Wg_b, xw_h, xw_l);

    // G3: M=2048,N=4096,K=1024
    mfma_split_gemm<<<dim3(32, 16, 1), 256, 0, stream>>>(
        xw_h, xw_l, hWT_h, hWT_l, hW_b, 1,
        hT_h, hT_l, nullptr, 0, 0,
        1024, 1024, 1024, 0, 0,
        7, 524288, 9, 65536, 128, 0, 0, 1);

    dot_pairs_hT<<<CHUNK_ * 8, 512, 0, stream>>>(hT_h, hT_l, ha_w, esrc, edst);
    edge_softmax_kernel<<<CHUNK_ * 8 * 128, 64, 0, stream>>>(
        esrc, edst, ha_b, adj + (size_t)b0 * 16384, nullptr, att_h, att_l, 8, 1);

    // x1T: per z=(bc,h): M=512(o),N=128(i),K=128(j)
    mfma_split_gemm<<<dim3(1, 4, CHUNK_ * 8), 256, 0, stream>>>(
        hT_h, hT_l, att_h, att_l, nullptr, 0,
        x1_h, x1_l, nullptr, 0, 1,
        128, 128, 128, 65536, 16384,
        9, 0, 7, 0, 4096, 524288, 512, 8);

    // G7 (split-K=4): M=2048,N=512,K=1024/slice
    mfma_split_gemm<<<dim3(4, 16, 4), 256, 0, stream>>>(
        x1_h, x1_l, oWT_h, oWT_l, nullptr, 0,
        nullptr, nullptr, ps, 1, 0,
        1024, 4096, 4096, 1024, 1024,
        13, 0, 9, 0, 2048, 0, 1048576, 4);
    reduce4_bias<<<1024, 256, 0, stream>>>(ps, oW_b, h2T, b0 * 128);
  }

  // attention-2 (fp32, unchunked)
  dot_pairs_h2T<<<64, 512, 0, stream>>>(h2T, oa_w, e2s, e2d);
  edge_softmax_kernel<<<8192, 64, 0, stream>>>(e2s, e2d, oa_b, adj,
      att2, nullptr, nullptr, 1, 0);
  bgemm_elu_bt_f32<<<dim3(16, 64), 256, 0, stream>>>(att2, h2T, x2);

  // logits + finalize
  logits_kernel<<<2048, 256, 0, stream>>>(x2, fin_w, fin_b, lgts, 8192);
  finalize_kernel<<<B_, 128, 0, stream>>>(lgts, tag, amask, ig, out);
}